// Round 1
// baseline (1265.201 us; speedup 1.0000x reference)
//
#include <hip/hip_runtime.h>
#include <math.h>

// ---------------------------------------------------------------------------
// RiemannianPooling: logm(eigh) -> mean -> diff_exp -> cov -> cholesky -> bimap
// N=32, M*T*V=3200, C=16, D=136, out 32x64x64 fp32.
// ---------------------------------------------------------------------------

#define EPSV 1e-4f
#define NSWEEP 10
#define SQRT2F 1.41421356237309515f

// workspace layout (float offsets)
#define OFF_G      0            // 136
#define OFF_WBT    160          // 137*64 = 8768
#define OFF_MEAN   8960         // 32*136
#define OFF_XM     13312        // 32*136
#define OFF_MPART  17664        // 5*32*136
#define OFF_T      39424        // 32*137*64
#define OFF_PART   320000       // 8*32*9316
#define OFF_L      2704896      // 102400*136  (ends 16,631,296 floats = 66.5MB)

__device__ __forceinline__ float rcp_f(float x){ return __builtin_amdgcn_rcpf(x); }
__device__ __forceinline__ float rsq_f(float x){ return __builtin_amdgcn_rsqf(x); }

template<int IMM>
__device__ __forceinline__ float swz(float x){
    return __int_as_float(__builtin_amdgcn_ds_swizzle(__float_as_int(x), IMM));
}

// decode linear lower-tri index d -> (r,c), d = r(r+1)/2 + c
__device__ __forceinline__ void tri_rc(int d, int &r, int &c){
    int rr = (int)floorf((sqrtf(fmaf(8.f, (float)d, 1.f)) - 1.f) * 0.5f);
    if (rr*(rr+1)/2 > d) rr--;
    if ((rr+1)*(rr+2)/2 <= d) rr++;
    r = rr; c = d - rr*(rr+1)/2;
}

// One XOR-tournament round of one-sided Jacobi. 16 threads per matrix.
// t = lane&15 (column index). Columns of B in b[16]. nrm = running ||b||^2.
template<int R, bool WV>
__device__ __forceinline__ void jac_round(float* b, float* v, float &nrm, int t){
    constexpr int IMM = (R << 10) | 0x1F;   // xor=R, and=0x1F
    float pc[16];
#pragma unroll
    for (int i = 0; i < 16; ++i) pc[i] = swz<IMM>(b[i]);
    float pn = swz<IMM>(nrm);
    float gam = 0.f;
#pragma unroll
    for (int i = 0; i < 16; ++i) gam = fmaf(b[i], pc[i], gam);
    constexpr int HB = (R & 8) ? 8 : ((R & 4) ? 4 : ((R & 2) ? 2 : 1));
    const bool isp = ((t & HB) == 0);           // this thread holds column p (p<q)
    float alpha = isp ? nrm : pn;
    float beta  = isp ? pn  : nrm;
    float zeta = (beta - alpha) * 0.5f * rcp_f(gam);
    float tt = copysignf(rcp_f(fabsf(zeta) + sqrtf(fmaf(zeta, zeta, 1.f))), zeta);
    tt = (gam == 0.f) ? 0.f : tt;
    float c = rsq_f(fmaf(tt, tt, 1.f));
    float s = tt * c;
    float ss = isp ? -s  : s;
    float st = isp ? -tt : tt;
#pragma unroll
    for (int i = 0; i < 16; ++i) b[i] = fmaf(c, b[i], ss * pc[i]);
    if (WV){
        float pv[16];
#pragma unroll
        for (int i = 0; i < 16; ++i) pv[i] = swz<IMM>(v[i]);
#pragma unroll
        for (int i = 0; i < 16; ++i) v[i] = fmaf(c, v[i], ss * pv[i]);
    }
    nrm = fmaf(st, gam, nrm);                   // alpha' = alpha - t*gam ; beta' = beta + t*gam
}

template<bool WV>
__device__ __forceinline__ void jac_sweep(float* b, float* v, float &nrm, int t){
    jac_round< 1,WV>(b,v,nrm,t); jac_round< 2,WV>(b,v,nrm,t); jac_round< 3,WV>(b,v,nrm,t);
    jac_round< 4,WV>(b,v,nrm,t); jac_round< 5,WV>(b,v,nrm,t); jac_round< 6,WV>(b,v,nrm,t);
    jac_round< 7,WV>(b,v,nrm,t); jac_round< 8,WV>(b,v,nrm,t); jac_round< 9,WV>(b,v,nrm,t);
    jac_round<10,WV>(b,v,nrm,t); jac_round<11,WV>(b,v,nrm,t); jac_round<12,WV>(b,v,nrm,t);
    jac_round<13,WV>(b,v,nrm,t); jac_round<14,WV>(b,v,nrm,t); jac_round<15,WV>(b,v,nrm,t);
}

// ---------------------------------------------------------------------------
// A: eigenvalues of W_sym -> s sorted desc -> G[136] = triScale * diff_exp factor.
//    Also transposes Wb into WbT[137][64].
__global__ __launch_bounds__(256) void k_prep(const float* __restrict__ W,
                                              const float* __restrict__ Wb,
                                              float* __restrict__ ws){
    __shared__ float sigv[16];
    __shared__ float s_srt[16];
    const int tid = threadIdx.x;
    const int t = tid & 15;
    if (tid < 64){
        float b[16]; float nrm = 0.f;
#pragma unroll
        for (int i = 0; i < 16; ++i){
            b[i] = 0.5f * (W[i*16 + t] + W[t*16 + i]);
            nrm = fmaf(b[i], b[i], nrm);
        }
#pragma unroll 1
        for (int sw = 0; sw < NSWEEP; ++sw) jac_sweep<false>(b, b, nrm, t);
        float n2 = 0.f;
#pragma unroll
        for (int i = 0; i < 16; ++i) n2 = fmaf(b[i], b[i], n2);
        float sig = sqrtf(n2);
        if (tid < 16) sigv[t] = sig;
    }
    __syncthreads();
    if (tid < 16){
        float sig = sigv[t];
        int rank = 0;
#pragma unroll
        for (int u = 0; u < 16; ++u){
            float su = sigv[u];
            rank += (su > sig || (su == sig && u < t)) ? 1 : 0;
        }
        s_srt[rank] = sig;   // descending, matches jnp.linalg.svd order
    }
    // transpose Wb [64][137] -> WbT [137][64]
    for (int e = tid; e < 8768; e += 256){
        int o = e / 137, i = e - o*137;
        ws[OFF_WBT + i*64 + o] = Wb[e];
    }
    __syncthreads();
    if (tid < 136){
        int r, c; tri_rc(tid, r, c);
        float sr = s_srt[r], sc = s_srt[c];
        float den = sr - sc;
        bool eq = fabsf(den) < EPSV;
        float er = expf(sr), ec = expf(sc);
        float num = eq ? 0.5f*(er + ec) : (er - ec);
        float dd  = eq ? 1.f : den;
        float scale = (r == c) ? 1.f : SQRT2F;
        ws[OFF_G + tid] = scale * num / dd;
    }
}

// ---------------------------------------------------------------------------
// B: per-matrix eigh + logm lower triangle. 16 threads/matrix, 16 matrices/block.
__global__ __launch_bounds__(256) void k_logm(const float* __restrict__ x,
                                              float* __restrict__ L){
    __shared__ __align__(16) float Bl[16][16][20];
    __shared__ __align__(16) float Hl[16][16][20];
    const int tid = threadIdx.x;
    const int t = tid & 15;
    const int g = tid >> 4;
    const size_t m = (size_t)blockIdx.x * 16 + g;   // 0..102399
    const float* xp = x + m * 256;
    float b[16]; float nrm = 0.f;
#pragma unroll
    for (int i = 0; i < 16; ++i){
        b[i] = xp[i*16 + t];
        nrm = fmaf(b[i], b[i], nrm);
    }
#pragma unroll 1
    for (int sw = 0; sw < NSWEEP; ++sw) jac_sweep<false>(b, b, nrm, t);
    // eigenvalue = ||b||, eigenvector = b/||b|| (SPD: eigs >= 0.5, clamp inert)
    float n2 = 0.f;
#pragma unroll
    for (int i = 0; i < 16; ++i) n2 = fmaf(b[i], b[i], n2);
    float lam = sqrtf(n2);
    float w = logf(fmaxf(lam, EPSV));
    float coef = w / n2;                    // logm = sum (w/lam^2) b b^T
#pragma unroll
    for (int i = 0; i < 16; ++i){ Bl[g][i][t] = b[i]; Hl[g][i][t] = b[i] * coef; }
    __syncthreads();
    float* Lp = L + m * 136;
#pragma unroll
    for (int k = 0; k < 9; ++k){
        int d = t + 16*k;
        if (d < 136){
            int r, c; tri_rc(d, r, c);
            float acc = 0.f;
#pragma unroll
            for (int j = 0; j < 16; ++j) acc = fmaf(Hl[g][r][j], Bl[g][c][j], acc);
            Lp[d] = acc;
        }
    }
}

// ---------------------------------------------------------------------------
// C: partial sums of L over p (5 chunks of 640 per n). Deterministic, no atomics.
__global__ __launch_bounds__(256) void k_meanpart(const float* __restrict__ L,
                                                  float* __restrict__ mpart){
    __shared__ __align__(16) float acc[7][136];
    const int bid = blockIdx.x;
    const int n = bid & 31, ch = bid >> 5;  // ch in 0..4
    const int tid = threadIdx.x;
    if (tid < 238){
        int d4 = tid % 34, ps = tid / 34;   // ps in 0..6
        float ax=0.f, ay=0.f, az=0.f, aw=0.f;
        const float* base = L + (size_t)n * 3200 * 136;
        for (int p = ch*640 + ps; p < ch*640 + 640; p += 7){
            const float4 v = *(const float4*)(base + (size_t)p*136 + d4*4);
            ax += v.x; ay += v.y; az += v.z; aw += v.w;
        }
        float4 r; r.x = ax; r.y = ay; r.z = az; r.w = aw;
        *(float4*)(&acc[ps][d4*4]) = r;
    }
    __syncthreads();
    if (tid < 136){
        float s = 0.f;
#pragma unroll
        for (int ps = 0; ps < 7; ++ps) s += acc[ps][tid];
        mpart[((size_t)ch*32 + n)*136 + tid] = s;
    }
}

// ---------------------------------------------------------------------------
// D: finalize mean, then xm = lower_triangle(sym_logm(x_mean)). V tracked so the
//    SIGNED eigenvalue (lam = v.b) feeds the EPS clamp (x_mean may be indefinite).
__global__ __launch_bounds__(64) void k_xm(float* __restrict__ ws){
    __shared__ float Ms[136];
    __shared__ float Vl[16][20];
    __shared__ float Hl2[16][20];
    const int n = blockIdx.x;
    const int tid = threadIdx.x;
    for (int d = tid; d < 136; d += 64){
        float s = 0.f;
#pragma unroll
        for (int ch = 0; ch < 5; ++ch) s += ws[OFF_MPART + ((size_t)ch*32 + n)*136 + d];
        s *= (1.f/3200.f);
        ws[OFF_MEAN + n*136 + d] = s;
        Ms[d] = s;
    }
    __syncthreads();
    const int t = tid & 15;
    float b[16], v[16]; float nrm = 0.f;
#pragma unroll
    for (int i = 0; i < 16; ++i){
        int r = (i > t) ? i : t, c = (i > t) ? t : i;
        b[i] = Ms[r*(r+1)/2 + c];
        v[i] = (i == t) ? 1.f : 0.f;
        nrm = fmaf(b[i], b[i], nrm);
    }
#pragma unroll 1
    for (int sw = 0; sw < NSWEEP; ++sw) jac_sweep<true>(b, v, nrm, t);
    float lam = 0.f;
#pragma unroll
    for (int i = 0; i < 16; ++i) lam = fmaf(v[i], b[i], lam);   // signed eigenvalue
    float w = logf(fmaxf(lam, EPSV));
    if (tid < 16){
#pragma unroll
        for (int i = 0; i < 16; ++i){ Vl[i][t] = v[i]; Hl2[i][t] = w * v[i]; }
    }
    __syncthreads();
    if (tid < 16){
        for (int k = 0; k < 9; ++k){
            int d = t + 16*k;
            if (d < 136){
                int r, c; tri_rc(d, r, c);
                float acc = 0.f;
#pragma unroll
                for (int j = 0; j < 16; ++j) acc = fmaf(Hl2[r][j], Vl[c][j], acc);
                float scale = (r == c) ? 1.f : SQRT2F;
                ws[OFF_XM + n*136 + d] = scale * acc;
            }
        }
    }
}

// ---------------------------------------------------------------------------
// E: partial covariance. xc = G*(L - mean). 8x4 register tiles, 8-p LDS stages.
__global__ __launch_bounds__(256) void k_cov(float* __restrict__ ws){
    __shared__ __align__(16) float xc[8][136];
    __shared__ __align__(16) float Gl[136];
    __shared__ __align__(16) float Ml[136];
    const int bid = blockIdx.x;
    const int n = bid & 31, c8 = bid >> 5;   // c8 in 0..7, 400 p each
    const int tid = threadIdx.x;
    if (tid < 136){
        Gl[tid] = ws[OFF_G + tid];
        Ml[tid] = ws[OFF_MEAN + n*136 + tid];
    }
    // decode this thread's tiles (8x4 blocks covering the lower triangle)
    int bi[2] = {0,0}, bj[2] = {0,0}; bool val[2] = {false,false};
#pragma unroll
    for (int s2 = 0; s2 < 2; ++s2){
        int T = tid + 256*s2;
        if (T < 306){
            int bb = (int)floorf((sqrtf(fmaf(4.f, (float)T, 1.f)) - 1.f) * 0.5f);
            while (bb*bb + bb > T) bb--;
            while ((bb+1)*(bb+1) + (bb+1) <= T) bb++;
            bi[s2] = bb; bj[s2] = T - bb*bb - bb; val[s2] = true;
        }
    }
    float a0[32], a1[32];
#pragma unroll
    for (int i = 0; i < 32; ++i){ a0[i] = 0.f; a1[i] = 0.f; }
    const float* Lbase = ws + OFF_L + (size_t)n * 3200 * 136;
    for (int st = 0; st < 50; ++st){
        __syncthreads();
        int p0 = c8*400 + st*8;
        for (int f = tid; f < 272; f += 256){
            int pp = f / 34, dd = f - pp*34;
            float4 lv = *(const float4*)(Lbase + (size_t)(p0+pp)*136 + dd*4);
            float4 gv = *(const float4*)(&Gl[dd*4]);
            float4 mv = *(const float4*)(&Ml[dd*4]);
            float4 r;
            r.x = (lv.x - mv.x) * gv.x; r.y = (lv.y - mv.y) * gv.y;
            r.z = (lv.z - mv.z) * gv.z; r.w = (lv.w - mv.w) * gv.w;
            *(float4*)(&xc[pp][dd*4]) = r;
        }
        __syncthreads();
#pragma unroll 1
        for (int pp = 0; pp < 8; ++pp){
            if (val[0]){
                const float4 u0 = *(const float4*)(&xc[pp][bi[0]*8]);
                const float4 u1 = *(const float4*)(&xc[pp][bi[0]*8+4]);
                const float4 w4 = *(const float4*)(&xc[pp][bj[0]*4]);
                float ui[8] = {u0.x,u0.y,u0.z,u0.w,u1.x,u1.y,u1.z,u1.w};
                float wj[4] = {w4.x,w4.y,w4.z,w4.w};
#pragma unroll
                for (int di = 0; di < 8; ++di)
#pragma unroll
                    for (int dj = 0; dj < 4; ++dj)
                        a0[di*4+dj] = fmaf(ui[di], wj[dj], a0[di*4+dj]);
            }
            if (val[1]){
                const float4 u0 = *(const float4*)(&xc[pp][bi[1]*8]);
                const float4 u1 = *(const float4*)(&xc[pp][bi[1]*8+4]);
                const float4 w4 = *(const float4*)(&xc[pp][bj[1]*4]);
                float ui[8] = {u0.x,u0.y,u0.z,u0.w,u1.x,u1.y,u1.z,u1.w};
                float wj[4] = {w4.x,w4.y,w4.z,w4.w};
#pragma unroll
                for (int di = 0; di < 8; ++di)
#pragma unroll
                    for (int dj = 0; dj < 4; ++dj)
                        a1[di*4+dj] = fmaf(ui[di], wj[dj], a1[di*4+dj]);
            }
        }
    }
    float* part = ws + OFF_PART + ((size_t)c8*32 + n)*9316;
#pragma unroll
    for (int s2 = 0; s2 < 2; ++s2){
        if (!val[s2]) continue;
        const float* a = (s2 == 0) ? a0 : a1;
#pragma unroll
        for (int di = 0; di < 8; ++di){
            int i = bi[s2]*8 + di;
#pragma unroll
            for (int dj = 0; dj < 4; ++dj){
                int j = bj[s2]*4 + dj;
                if (j <= i) part[i*(i+1)/2 + j] = a[di*4+dj];
            }
        }
    }
}

// ---------------------------------------------------------------------------
// F1: sum partials -> cov -> Cholesky (tri-packed LDS) -> trace -> Tout = outM*Wb^T
__global__ __launch_bounds__(256) void k_chol(float* __restrict__ ws){
    __shared__ float T[9316];
    __shared__ float xr[137];
    __shared__ float trs[2];
    const int n = blockIdx.x;
    const int tid = threadIdx.x;
    for (int e = tid; e < 9316; e += 256){
        float s = 0.f;
#pragma unroll
        for (int c = 0; c < 8; ++c) s += ws[OFF_PART + ((size_t)c*32 + n)*9316 + e];
        T[e] = s * (1.f/3199.f);
    }
    if (tid < 136) xr[tid] = ws[OFF_XM + n*136 + tid];
    __syncthreads();
    for (int k = 0; k < 136; ++k){
        const int kb = k*(k+1)/2;
        float dkk = T[kb + k];
        float d = sqrtf(dkk);
        float rinv = 1.f / d;
        __syncthreads();
        for (int i = k+1+tid; i < 136; i += 256) T[i*(i+1)/2 + k] *= rinv;
        if (tid == 0) T[kb + k] = d;
        __syncthreads();
        const int m = 135 - k;
        const int cnt = m*(m+1)/2;
        const int Lc = (cnt + 255) >> 8;
        int e0 = tid * Lc, e1 = e0 + Lc; if (e1 > cnt) e1 = cnt;
        if (e0 < e1){
            float A = 2.f*m + 1.f;
            int jp = (int)floorf((A - sqrtf(fmaf(A, A, -8.f*e0))) * 0.5f);
            if (jp < 0) jp = 0;
            while (jp > 0 && jp*m - jp*(jp-1)/2 > e0) jp--;
            while ((jp+1)*m - (jp+1)*jp/2 <= e0) jp++;
            int ip = jp + (e0 - (jp*m - jp*(jp-1)/2));
            int i = k+1+ip, j = k+1+jp;
            int bI = i*(i+1)/2;
            int idx_ij = bI + j, idx_ik = bI + k;
            float cj = T[j*(j+1)/2 + k];
            for (int e = e0; e < e1; ++e){
                T[idx_ij] -= T[idx_ik] * cj;
                i++;
                if (i == 136){
                    j++; i = j;
                    int bb = i*(i+1)/2;
                    idx_ij = bb + j; idx_ik = bb + k;
                    cj = T[idx_ik];
                } else {
                    idx_ij += i; idx_ik += i;
                }
            }
        }
        __syncthreads();
    }
    if (tid == 0){
        float tr = 1.f;
        for (int kk = 0; kk < 136; ++kk) tr += T[kk*(kk+1)/2 + kk];
        trs[0] = tr; trs[1] = 1.f / tr;
    }
    __syncthreads();
    const float tr = trs[0], itr = trs[1];
    const float c6 = tr * 1e-6f;
    const float* WbT = ws + OFF_WBT;
    float* Tout = ws + OFF_T + (size_t)n * 8768;
    const int q = tid & 63, wv = tid >> 6;
    for (int i = wv; i <= 136; i += 4){
        float accv;
        if (i < 136){
            const int ib = i*(i+1)/2;
            float acc = 0.f;
            for (int j = 0; j <= i; ++j) acc = fmaf(T[ib + j], WbT[j*64 + q], acc);
            accv = fmaf(c6, WbT[i*64 + q], itr * acc);
        } else {
            float acc = WbT[136*64 + q];               // out[D][D] = 1
            for (int j = 0; j < 136; ++j) acc = fmaf(xr[j], WbT[j*64 + q], acc);
            accv = fmaf(c6, WbT[136*64 + q], itr * acc);
        }
        Tout[i*64 + q] = accv;
    }
}

// ---------------------------------------------------------------------------
// F2: res[n] = Wb @ Tout[n]  -> d_out [32][64][64]
__global__ __launch_bounds__(256) void k_bimap(const float* __restrict__ ws,
                                               const float* __restrict__ Wb,
                                               float* __restrict__ out){
    const int n = blockIdx.x;
    const int tid = threadIdx.x;
    const int q = tid & 63, ob = tid >> 6;
    const float* Tn = ws + OFF_T + (size_t)n * 8768;
#pragma unroll 1
    for (int o = ob; o < 64; o += 4){
        float acc = 0.f;
        const float* wr = Wb + o*137;
        for (int i = 0; i < 137; ++i) acc = fmaf(wr[i], Tn[i*64 + q], acc);
        out[(size_t)n*4096 + o*64 + q] = acc;
    }
}

// ---------------------------------------------------------------------------
extern "C" void kernel_launch(void* const* d_in, const int* in_sizes, int n_in,
                              void* d_out, int out_size, void* d_ws, size_t ws_size,
                              hipStream_t stream){
    const float* x   = (const float*)d_in[0];
    const float* W   = (const float*)d_in[1];
    const float* Wb  = (const float*)d_in[2];
    float* out = (float*)d_out;
    float* ws  = (float*)d_ws;

    k_prep    <<<   1, 256, 0, stream>>>(W, Wb, ws);
    k_logm    <<<6400, 256, 0, stream>>>(x, ws + OFF_L);
    k_meanpart<<< 160, 256, 0, stream>>>(ws + OFF_L, ws + OFF_MPART);
    k_xm      <<<  32,  64, 0, stream>>>(ws);
    k_cov     <<< 256, 256, 0, stream>>>(ws);
    k_chol    <<<  32, 256, 0, stream>>>(ws);
    k_bimap   <<<  32, 256, 0, stream>>>(ws, Wb, out);
}

// Round 2
// 1263.297 us; speedup vs baseline: 1.0015x; 1.0015x over previous
//
#include <hip/hip_runtime.h>
#include <math.h>

// ---------------------------------------------------------------------------
// RiemannianPooling: logm(eigh) -> mean -> diff_exp -> cov -> cholesky -> bimap
// N=32, M*T*V=3200, C=16, D=136, out 32x64x64 fp32.
// R2: DPP-only Jacobi (no ds_swizzle), packed f32 math, 8 sweeps, fused mean
//     partials into k_logm, LDS-staged bimap.
// ---------------------------------------------------------------------------

#define EPSV 1e-4f
#define NSWEEP_BIG 8
#define NSWEEP_SMALL 10
#define SQRT2F 1.41421356237309515f

// workspace layout (float offsets) — total 66.5 MB
#define OFF_G      0            // 136
#define OFF_WBT    160          // 137*64 = 8768
#define OFF_MEAN   8960         // 32*136
#define OFF_XM     13312        // 32*136
#define OFF_T      39424        // 32*137*64
#define OFF_PART   320000       // 8*32*9316
#define OFF_MPART  320000       // alias: 6400*136 (consumed by k_xm before k_cov writes)
#define OFF_L      2704896      // 102400*136

typedef float v2f __attribute__((ext_vector_type(2)));

__device__ __forceinline__ float rcp_f(float x){ return __builtin_amdgcn_rcpf(x); }
__device__ __forceinline__ float rsq_f(float x){ return __builtin_amdgcn_rsqf(x); }

// Cross-lane XOR within rows of 16 via DPP only (VALU pipe, no LDS traffic).
// XOR1/2/3: quad_perm; XOR7: row_half_mirror; XOR8: row_ror:8; XOR15: row_mirror.
// Everything else composes as two DPP movs.
template<int R>
__device__ __forceinline__ float xl(float x){
    int s = __float_as_int(x);
    if constexpr (R == 1){
        return __int_as_float(__builtin_amdgcn_update_dpp(s, s, 0xB1, 0xF, 0xF, false));
    } else if constexpr (R == 2){
        return __int_as_float(__builtin_amdgcn_update_dpp(s, s, 0x4E, 0xF, 0xF, false));
    } else if constexpr (R == 3){
        return __int_as_float(__builtin_amdgcn_update_dpp(s, s, 0x1B, 0xF, 0xF, false));
    } else if constexpr (R == 7){
        return __int_as_float(__builtin_amdgcn_update_dpp(s, s, 0x141, 0xF, 0xF, false));
    } else if constexpr (R == 8){
        return __int_as_float(__builtin_amdgcn_update_dpp(s, s, 0x128, 0xF, 0xF, false));
    } else if constexpr (R == 15){
        return __int_as_float(__builtin_amdgcn_update_dpp(s, s, 0x140, 0xF, 0xF, false));
    } else if constexpr (R < 8){            // 4,5,6 = (R^7) then 7
        return xl<7>(xl<R^7>(x));
    } else if constexpr (R < 12){           // 9,10,11 = (R^8) then 8
        return xl<8>(xl<R^8>(x));
    } else {                                // 12,13,14 = (R^15) then 15
        return xl<15>(xl<R^15>(x));
    }
}

// decode linear lower-tri index d -> (r,c), d = r(r+1)/2 + c
__device__ __forceinline__ void tri_rc(int d, int &r, int &c){
    int rr = (int)floorf((sqrtf(fmaf(8.f, (float)d, 1.f)) - 1.f) * 0.5f);
    if (rr*(rr+1)/2 > d) rr--;
    if ((rr+1)*(rr+2)/2 <= d) rr++;
    r = rr; c = d - rr*(rr+1)/2;
}

// One XOR-tournament round of one-sided Jacobi. 16 lanes per matrix.
// t = lane&15 (column index). Columns of B as 8 float2 in regs. nrm = ||b||^2.
template<int R, bool WV>
__device__ __forceinline__ void jac_round(v2f* b, v2f* v, float &nrm, int t){
    v2f pc[8];
#pragma unroll
    for (int i = 0; i < 8; ++i){ pc[i].x = xl<R>(b[i].x); pc[i].y = xl<R>(b[i].y); }
    float pn = xl<R>(nrm);
    v2f g2 = {0.f, 0.f};
#pragma unroll
    for (int i = 0; i < 8; ++i) g2 = g2 + b[i]*pc[i];    // v_pk_fma_f32
    float gam = g2.x + g2.y;
    constexpr int HB = (R & 8) ? 8 : ((R & 4) ? 4 : ((R & 2) ? 2 : 1)); // highest bit: p<q
    const bool isp = ((t & HB) == 0);
    float alpha = isp ? nrm : pn;
    float beta  = isp ? pn  : nrm;
    float zeta = (beta - alpha) * 0.5f * rcp_f(gam);
    float tt = copysignf(rcp_f(fabsf(zeta) + sqrtf(fmaf(zeta, zeta, 1.f))), zeta);
    tt = (gam == 0.f) ? 0.f : tt;
    float c = rsq_f(fmaf(tt, tt, 1.f));
    float s = tt * c;
    float ss = isp ? -s  : s;
    float st = isp ? -tt : tt;
    v2f cv = {c, c};
    v2f sv = {ss, ss};
#pragma unroll
    for (int i = 0; i < 8; ++i) b[i] = b[i]*cv + pc[i]*sv;   // pk_mul + pk_fma
    if (WV){
        v2f pv[8];
#pragma unroll
        for (int i = 0; i < 8; ++i){ pv[i].x = xl<R>(v[i].x); pv[i].y = xl<R>(v[i].y); }
#pragma unroll
        for (int i = 0; i < 8; ++i) v[i] = v[i]*cv + pv[i]*sv;
    }
    nrm = fmaf(st, gam, nrm);
}

template<bool WV>
__device__ __forceinline__ void jac_sweep(v2f* b, v2f* v, float &nrm, int t){
    jac_round< 1,WV>(b,v,nrm,t); jac_round< 2,WV>(b,v,nrm,t); jac_round< 3,WV>(b,v,nrm,t);
    jac_round< 4,WV>(b,v,nrm,t); jac_round< 5,WV>(b,v,nrm,t); jac_round< 6,WV>(b,v,nrm,t);
    jac_round< 7,WV>(b,v,nrm,t); jac_round< 8,WV>(b,v,nrm,t); jac_round< 9,WV>(b,v,nrm,t);
    jac_round<10,WV>(b,v,nrm,t); jac_round<11,WV>(b,v,nrm,t); jac_round<12,WV>(b,v,nrm,t);
    jac_round<13,WV>(b,v,nrm,t); jac_round<14,WV>(b,v,nrm,t); jac_round<15,WV>(b,v,nrm,t);
}

// ---------------------------------------------------------------------------
// A: s = svd(W_sym) desc -> G[136] = triScale * diff_exp factor; WbT transpose.
__global__ __launch_bounds__(256) void k_prep(const float* __restrict__ W,
                                              const float* __restrict__ Wb,
                                              float* __restrict__ ws){
    __shared__ float sigv[16];
    __shared__ float s_srt[16];
    const int tid = threadIdx.x;
    const int t = tid & 15;
    if (tid < 64){
        v2f b[8]; float nrm = 0.f;
        float* bf = (float*)b;
#pragma unroll
        for (int i = 0; i < 16; ++i){
            float val = 0.5f * (W[i*16 + t] + W[t*16 + i]);
            bf[i] = val;
            nrm = fmaf(val, val, nrm);
        }
#pragma unroll 1
        for (int sw = 0; sw < NSWEEP_SMALL; ++sw) jac_sweep<false>(b, b, nrm, t);
        float n2 = 0.f;
#pragma unroll
        for (int i = 0; i < 16; ++i) n2 = fmaf(bf[i], bf[i], n2);
        float sig = sqrtf(n2);
        if (tid < 16) sigv[t] = sig;
    }
    __syncthreads();
    if (tid < 16){
        float sig = sigv[t];
        int rank = 0;
#pragma unroll
        for (int u = 0; u < 16; ++u){
            float su = sigv[u];
            rank += (su > sig || (su == sig && u < t)) ? 1 : 0;
        }
        s_srt[rank] = sig;   // descending, matches jnp.linalg.svd order
    }
    // transpose Wb [64][137] -> WbT [137][64]
    for (int e = tid; e < 8768; e += 256){
        int o = e / 137, i = e - o*137;
        ws[OFF_WBT + i*64 + o] = Wb[e];
    }
    __syncthreads();
    if (tid < 136){
        int r, c; tri_rc(tid, r, c);
        float sr = s_srt[r], sc = s_srt[c];
        float den = sr - sc;
        bool eq = fabsf(den) < EPSV;
        float er = expf(sr), ec = expf(sc);
        float num = eq ? 0.5f*(er + ec) : (er - ec);
        float dd  = eq ? 1.f : den;
        float scale = (r == c) ? 1.f : SQRT2F;
        ws[OFF_G + tid] = scale * num / dd;
    }
}

// ---------------------------------------------------------------------------
// B: per-matrix eigh + logm lower triangle + per-block mean partials.
//    16 lanes/matrix, 16 matrices/block. LDS 18.4 KB -> 8 blocks/CU.
__global__ __launch_bounds__(256) void k_logm(const float* __restrict__ x,
                                              float* __restrict__ L,
                                              float* __restrict__ mpart){
    __shared__ float sm[4608];     // Bl[g][16][17] (4352) + cof[g][16] (256)
    float* Bl  = sm;               // g*272 + i*17 + t
    float* cof = sm + 4352;        // g*16 + j
    const int tid = threadIdx.x;
    const int t = tid & 15;
    const int g = tid >> 4;
    const size_t m = (size_t)blockIdx.x * 16 + g;
    const float* xp = x + m * 256;
    v2f b[8]; float nrm = 0.f;
    float* bf = (float*)b;
#pragma unroll
    for (int i = 0; i < 16; ++i){
        float val = xp[i*16 + t];
        bf[i] = val;
        nrm = fmaf(val, val, nrm);
    }
#pragma unroll 1
    for (int sw = 0; sw < NSWEEP_BIG; ++sw) jac_sweep<false>(b, b, nrm, t);
    // eigenvalue = ||b||, eigenvector = b/||b|| (SPD: eigs >= 0.5, clamp inert)
    float n2 = 0.f;
#pragma unroll
    for (int i = 0; i < 16; ++i) n2 = fmaf(bf[i], bf[i], n2);
    float lam = sqrtf(n2);
    float w = logf(fmaxf(lam, EPSV));
    float coef = w / n2;            // logm = sum_j coef_j b_j b_j^T
#pragma unroll
    for (int i = 0; i < 16; ++i) Bl[g*272 + i*17 + t] = bf[i];
    cof[g*16 + t] = coef;
    __syncthreads();
    float outv[9];
    float* Lp = L + m * 136;
#pragma unroll
    for (int k = 0; k < 9; ++k){
        int d = t + 16*k;
        float acc = 0.f;
        if (d < 136){
            int r, c; tri_rc(d, r, c);
#pragma unroll
            for (int j = 0; j < 16; ++j)
                acc = fmaf(cof[g*16 + j] * Bl[g*272 + r*17 + j], Bl[g*272 + c*17 + j], acc);
            Lp[d] = acc;
        }
        outv[k] = acc;
    }
    __syncthreads();                // all Bl reads done; alias as reduction buffer
    float* red = sm;                // red[g*144 + d]
#pragma unroll
    for (int k = 0; k < 9; ++k){
        int d = t + 16*k;
        red[g*144 + d] = outv[k];   // d in [0,144); zeros for d>=136
    }
    __syncthreads();
    if (tid < 136){
        float s = 0.f;
#pragma unroll
        for (int gg = 0; gg < 16; ++gg) s += red[gg*144 + tid];
        mpart[(size_t)blockIdx.x * 136 + tid] = s;
    }
}

// ---------------------------------------------------------------------------
// D: finalize mean (sum 200 block-partials), then xm = lower_triangle(sym_logm(mean)).
//    V tracked so the SIGNED eigenvalue (lam = v.b) feeds the EPS clamp.
__global__ __launch_bounds__(256) void k_xm(float* __restrict__ ws){
    __shared__ float Ms[136];
    __shared__ float Vl[16][20];
    __shared__ float Hl2[16][20];
    const int n = blockIdx.x;
    const int tid = threadIdx.x;
    if (tid < 136){
        const float* mp = ws + OFF_MPART + (size_t)n * 200 * 136 + tid;
        float s = 0.f;
#pragma unroll 4
        for (int c = 0; c < 200; ++c) s += mp[(size_t)c * 136];
        s *= (1.f/3200.f);
        ws[OFF_MEAN + n*136 + tid] = s;
        Ms[tid] = s;
    }
    __syncthreads();
    const int t = tid & 15;
    if (tid < 64){
        v2f b[8], v[8]; float nrm = 0.f;
        float* bf = (float*)b;
        float* vf = (float*)v;
#pragma unroll
        for (int i = 0; i < 16; ++i){
            int r = (i > t) ? i : t, c = (i > t) ? t : i;
            bf[i] = Ms[r*(r+1)/2 + c];
            vf[i] = (i == t) ? 1.f : 0.f;
            nrm = fmaf(bf[i], bf[i], nrm);
        }
#pragma unroll 1
        for (int sw = 0; sw < NSWEEP_SMALL; ++sw) jac_sweep<true>(b, v, nrm, t);
        float lam = 0.f;
#pragma unroll
        for (int i = 0; i < 16; ++i) lam = fmaf(vf[i], bf[i], lam);  // signed eig
        float w = logf(fmaxf(lam, EPSV));
        if (tid < 16){
#pragma unroll
            for (int i = 0; i < 16; ++i){ Vl[i][t] = vf[i]; Hl2[i][t] = w * vf[i]; }
        }
    }
    __syncthreads();
    if (tid < 16){
        for (int k = 0; k < 9; ++k){
            int d = t + 16*k;
            if (d < 136){
                int r, c; tri_rc(d, r, c);
                float acc = 0.f;
#pragma unroll
                for (int j = 0; j < 16; ++j) acc = fmaf(Hl2[r][j], Vl[c][j], acc);
                float scale = (r == c) ? 1.f : SQRT2F;
                ws[OFF_XM + n*136 + d] = scale * acc;
            }
        }
    }
}

// ---------------------------------------------------------------------------
// E: partial covariance. xc = G*(L - mean). 8x4 register tiles, 8-p LDS stages.
__global__ __launch_bounds__(256) void k_cov(float* __restrict__ ws){
    __shared__ __align__(16) float xc[8][136];
    __shared__ __align__(16) float Gl[136];
    __shared__ __align__(16) float Ml[136];
    const int bid = blockIdx.x;
    const int n = bid & 31, c8 = bid >> 5;   // c8 in 0..7, 400 p each
    const int tid = threadIdx.x;
    if (tid < 136){
        Gl[tid] = ws[OFF_G + tid];
        Ml[tid] = ws[OFF_MEAN + n*136 + tid];
    }
    int bi[2] = {0,0}, bj[2] = {0,0}; bool val[2] = {false,false};
#pragma unroll
    for (int s2 = 0; s2 < 2; ++s2){
        int T = tid + 256*s2;
        if (T < 306){
            int bb = (int)floorf((sqrtf(fmaf(4.f, (float)T, 1.f)) - 1.f) * 0.5f);
            while (bb*bb + bb > T) bb--;
            while ((bb+1)*(bb+1) + (bb+1) <= T) bb++;
            bi[s2] = bb; bj[s2] = T - bb*bb - bb; val[s2] = true;
        }
    }
    float a0[32], a1[32];
#pragma unroll
    for (int i = 0; i < 32; ++i){ a0[i] = 0.f; a1[i] = 0.f; }
    const float* Lbase = ws + OFF_L + (size_t)n * 3200 * 136;
    for (int st = 0; st < 50; ++st){
        __syncthreads();
        int p0 = c8*400 + st*8;
        for (int f = tid; f < 272; f += 256){
            int pp = f / 34, dd = f - pp*34;
            float4 lv = *(const float4*)(Lbase + (size_t)(p0+pp)*136 + dd*4);
            float4 gv = *(const float4*)(&Gl[dd*4]);
            float4 mv = *(const float4*)(&Ml[dd*4]);
            float4 r;
            r.x = (lv.x - mv.x) * gv.x; r.y = (lv.y - mv.y) * gv.y;
            r.z = (lv.z - mv.z) * gv.z; r.w = (lv.w - mv.w) * gv.w;
            *(float4*)(&xc[pp][dd*4]) = r;
        }
        __syncthreads();
#pragma unroll 1
        for (int pp = 0; pp < 8; ++pp){
            if (val[0]){
                const float4 u0 = *(const float4*)(&xc[pp][bi[0]*8]);
                const float4 u1 = *(const float4*)(&xc[pp][bi[0]*8+4]);
                const float4 w4 = *(const float4*)(&xc[pp][bj[0]*4]);
                float ui[8] = {u0.x,u0.y,u0.z,u0.w,u1.x,u1.y,u1.z,u1.w};
                float wj[4] = {w4.x,w4.y,w4.z,w4.w};
#pragma unroll
                for (int di = 0; di < 8; ++di)
#pragma unroll
                    for (int dj = 0; dj < 4; ++dj)
                        a0[di*4+dj] = fmaf(ui[di], wj[dj], a0[di*4+dj]);
            }
            if (val[1]){
                const float4 u0 = *(const float4*)(&xc[pp][bi[1]*8]);
                const float4 u1 = *(const float4*)(&xc[pp][bi[1]*8+4]);
                const float4 w4 = *(const float4*)(&xc[pp][bj[1]*4]);
                float ui[8] = {u0.x,u0.y,u0.z,u0.w,u1.x,u1.y,u1.z,u1.w};
                float wj[4] = {w4.x,w4.y,w4.z,w4.w};
#pragma unroll
                for (int di = 0; di < 8; ++di)
#pragma unroll
                    for (int dj = 0; dj < 4; ++dj)
                        a1[di*4+dj] = fmaf(ui[di], wj[dj], a1[di*4+dj]);
            }
        }
    }
    float* part = ws + OFF_PART + ((size_t)c8*32 + n)*9316;
#pragma unroll
    for (int s2 = 0; s2 < 2; ++s2){
        if (!val[s2]) continue;
        const float* a = (s2 == 0) ? a0 : a1;
#pragma unroll
        for (int di = 0; di < 8; ++di){
            int i = bi[s2]*8 + di;
#pragma unroll
            for (int dj = 0; dj < 4; ++dj){
                int j = bj[s2]*4 + dj;
                if (j <= i) part[i*(i+1)/2 + j] = a[di*4+dj];
            }
        }
    }
}

// ---------------------------------------------------------------------------
// F1: sum partials -> cov -> Cholesky (tri-packed LDS) -> trace -> Tout = outM*WbT
__global__ __launch_bounds__(256) void k_chol(float* __restrict__ ws){
    __shared__ float T[9316];
    __shared__ float xr[137];
    __shared__ float trs[2];
    const int n = blockIdx.x;
    const int tid = threadIdx.x;
    for (int e = tid; e < 9316; e += 256){
        float s = 0.f;
#pragma unroll
        for (int c = 0; c < 8; ++c) s += ws[OFF_PART + ((size_t)c*32 + n)*9316 + e];
        T[e] = s * (1.f/3199.f);
    }
    if (tid < 136) xr[tid] = ws[OFF_XM + n*136 + tid];
    __syncthreads();
    for (int k = 0; k < 136; ++k){
        const int kb = k*(k+1)/2;
        float dkk = T[kb + k];
        float d = sqrtf(dkk);
        float rinv = 1.f / d;
        __syncthreads();
        for (int i = k+1+tid; i < 136; i += 256) T[i*(i+1)/2 + k] *= rinv;
        if (tid == 0) T[kb + k] = d;
        __syncthreads();
        const int m = 135 - k;
        const int cnt = m*(m+1)/2;
        const int Lc = (cnt + 255) >> 8;
        int e0 = tid * Lc, e1 = e0 + Lc; if (e1 > cnt) e1 = cnt;
        if (e0 < e1){
            float A = 2.f*m + 1.f;
            int jp = (int)floorf((A - sqrtf(fmaf(A, A, -8.f*e0))) * 0.5f);
            if (jp < 0) jp = 0;
            while (jp > 0 && jp*m - jp*(jp-1)/2 > e0) jp--;
            while ((jp+1)*m - (jp+1)*jp/2 <= e0) jp++;
            int ip = jp + (e0 - (jp*m - jp*(jp-1)/2));
            int i = k+1+ip, j = k+1+jp;
            int bI = i*(i+1)/2;
            int idx_ij = bI + j, idx_ik = bI + k;
            float cj = T[j*(j+1)/2 + k];
            for (int e = e0; e < e1; ++e){
                T[idx_ij] -= T[idx_ik] * cj;
                i++;
                if (i == 136){
                    j++; i = j;
                    int bb = i*(i+1)/2;
                    idx_ij = bb + j; idx_ik = bb + k;
                    cj = T[idx_ik];
                } else {
                    idx_ij += i; idx_ik += i;
                }
            }
        }
        __syncthreads();
    }
    if (tid == 0){
        float tr = 1.f;
        for (int kk = 0; kk < 136; ++kk) tr += T[kk*(kk+1)/2 + kk];
        trs[0] = tr; trs[1] = 1.f / tr;
    }
    __syncthreads();
    const float tr = trs[0], itr = trs[1];
    const float c6 = tr * 1e-6f;
    const float* WbT = ws + OFF_WBT;
    float* Tout = ws + OFF_T + (size_t)n * 8768;
    const int q = tid & 63, wv = tid >> 6;
    for (int i = wv; i <= 136; i += 4){
        float accv;
        if (i < 136){
            const int ib = i*(i+1)/2;
            float acc = 0.f;
            for (int j = 0; j <= i; ++j) acc = fmaf(T[ib + j], WbT[j*64 + q], acc);
            accv = fmaf(c6, WbT[i*64 + q], itr * acc);
        } else {
            float acc = WbT[136*64 + q];               // out[D][D] = 1
            for (int j = 0; j < 136; ++j) acc = fmaf(xr[j], WbT[j*64 + q], acc);
            accv = fmaf(c6, WbT[136*64 + q], itr * acc);
        }
        Tout[i*64 + q] = accv;
    }
}

// ---------------------------------------------------------------------------
// F2: res[n] = Wb @ Tout[n]  -> d_out [32][64][64]. Tout staged in LDS.
__global__ __launch_bounds__(256) void k_bimap(const float* __restrict__ ws,
                                               const float* __restrict__ Wb,
                                               float* __restrict__ out){
    __shared__ float Tl[8768];
    const int n = blockIdx.x;
    const int tid = threadIdx.x;
    const float* Tn = ws + OFF_T + (size_t)n * 8768;
    for (int e = tid; e < 8768; e += 256) Tl[e] = Tn[e];
    __syncthreads();
    const int q = tid & 63, ob = tid >> 6;
#pragma unroll 1
    for (int o = ob; o < 64; o += 4){
        float acc = 0.f;
        const float* wr = Wb + o*137;
        for (int i = 0; i < 137; ++i) acc = fmaf(wr[i], Tl[i*64 + q], acc);
        out[(size_t)n*4096 + o*64 + q] = acc;
    }
}

// ---------------------------------------------------------------------------
extern "C" void kernel_launch(void* const* d_in, const int* in_sizes, int n_in,
                              void* d_out, int out_size, void* d_ws, size_t ws_size,
                              hipStream_t stream){
    const float* x   = (const float*)d_in[0];
    const float* W   = (const float*)d_in[1];
    const float* Wb  = (const float*)d_in[2];
    float* out = (float*)d_out;
    float* ws  = (float*)d_ws;

    k_prep <<<   1, 256, 0, stream>>>(W, Wb, ws);
    k_logm <<<6400, 256, 0, stream>>>(x, ws + OFF_L, ws + OFF_MPART);
    k_xm   <<<  32, 256, 0, stream>>>(ws);
    k_cov  <<< 256, 256, 0, stream>>>(ws);
    k_chol <<<  32, 256, 0, stream>>>(ws);
    k_bimap<<<  32, 256, 0, stream>>>(ws, Wb, out);
}

// Round 3
// 1129.132 us; speedup vs baseline: 1.1205x; 1.1188x over previous
//
#include <hip/hip_runtime.h>
#include <math.h>

// ---------------------------------------------------------------------------
// RiemannianPooling: logm(eigh) -> mean -> diff_exp -> cov -> cholesky -> bimap
// N=32, M*T*V=3200, C=16, D=136, out 32x64x64 fp32.
// R3: hybrid shuffle Jacobi — masks {1..8,15} on VALU via DPP, masks {9..14}
//     on the DS pipe via ds_swizzle, so both pipes run concurrently.
//     k_cov widened to 512 threads (1 tile/thread).
// ---------------------------------------------------------------------------

#define EPSV 1e-4f
#define NSWEEP_BIG 8
#define NSWEEP_SMALL 10
#define SQRT2F 1.41421356237309515f

// workspace layout (float offsets) — total 66.5 MB
#define OFF_G      0            // 136
#define OFF_WBT    160          // 137*64 = 8768
#define OFF_MEAN   8960         // 32*136
#define OFF_XM     13312        // 32*136
#define OFF_T      39424        // 32*137*64
#define OFF_PART   320000       // 8*32*9316
#define OFF_MPART  320000       // alias: 6400*136 (consumed by k_xm before k_cov writes)
#define OFF_L      2704896      // 102400*136

typedef float v2f __attribute__((ext_vector_type(2)));

__device__ __forceinline__ float rcp_f(float x){ return __builtin_amdgcn_rcpf(x); }
__device__ __forceinline__ float rsq_f(float x){ return __builtin_amdgcn_rsqf(x); }

// XOR within 16-lane rows via DPP (VALU pipe). Single-instr: 1,2,3 quad_perm;
// 7 row_half_mirror; 8 row_ror:8; 15 row_mirror. 4,5,6 compose with 7.
template<int R>
__device__ __forceinline__ float xl(float x){
    int s = __float_as_int(x);
    if constexpr (R == 1){
        return __int_as_float(__builtin_amdgcn_update_dpp(s, s, 0xB1, 0xF, 0xF, false));
    } else if constexpr (R == 2){
        return __int_as_float(__builtin_amdgcn_update_dpp(s, s, 0x4E, 0xF, 0xF, false));
    } else if constexpr (R == 3){
        return __int_as_float(__builtin_amdgcn_update_dpp(s, s, 0x1B, 0xF, 0xF, false));
    } else if constexpr (R == 7){
        return __int_as_float(__builtin_amdgcn_update_dpp(s, s, 0x141, 0xF, 0xF, false));
    } else if constexpr (R == 8){
        return __int_as_float(__builtin_amdgcn_update_dpp(s, s, 0x128, 0xF, 0xF, false));
    } else if constexpr (R == 15){
        return __int_as_float(__builtin_amdgcn_update_dpp(s, s, 0x140, 0xF, 0xF, false));
    } else {                                // 4,5,6 = (R^7) then 7
        return xl<7>(xl<R^7>(x));
    }
}

// Pipe-splitting shuffle: masks 9..14 go to the DS crossbar (ds_swizzle),
// the rest stay on the VALU DPP path.
template<int R>
__device__ __forceinline__ float shuf(float x){
    if constexpr (R >= 9 && R <= 14){
        constexpr int IMM = (R << 10) | 0x1F;   // BitMode: xor=R, and=0x1F
        return __int_as_float(__builtin_amdgcn_ds_swizzle(__float_as_int(x), IMM));
    } else {
        return xl<R>(x);
    }
}

// decode linear lower-tri index d -> (r,c), d = r(r+1)/2 + c
__device__ __forceinline__ void tri_rc(int d, int &r, int &c){
    int rr = (int)floorf((sqrtf(fmaf(8.f, (float)d, 1.f)) - 1.f) * 0.5f);
    if (rr*(rr+1)/2 > d) rr--;
    if ((rr+1)*(rr+2)/2 <= d) rr++;
    r = rr; c = d - rr*(rr+1)/2;
}

// One XOR-tournament round of one-sided Jacobi. 16 lanes per matrix.
// t = lane&15 (column index). Columns of B as 8 float2 in regs. nrm = ||b||^2.
template<int R, bool WV>
__device__ __forceinline__ void jac_round(v2f* b, v2f* v, float &nrm, int t){
    v2f pc[8];
#pragma unroll
    for (int i = 0; i < 8; ++i){ pc[i].x = shuf<R>(b[i].x); pc[i].y = shuf<R>(b[i].y); }
    float pn = shuf<R>(nrm);
    v2f g2 = {0.f, 0.f};
#pragma unroll
    for (int i = 0; i < 8; ++i) g2 = g2 + b[i]*pc[i];
    float gam = g2.x + g2.y;
    constexpr int HB = (R & 8) ? 8 : ((R & 4) ? 4 : ((R & 2) ? 2 : 1)); // highest bit: p<q
    const bool isp = ((t & HB) == 0);
    float alpha = isp ? nrm : pn;
    float beta  = isp ? pn  : nrm;
    float zeta = (beta - alpha) * 0.5f * rcp_f(gam);
    float tt = copysignf(rcp_f(fabsf(zeta) + sqrtf(fmaf(zeta, zeta, 1.f))), zeta);
    tt = (gam == 0.f) ? 0.f : tt;
    float c = rsq_f(fmaf(tt, tt, 1.f));
    float s = tt * c;
    float ss = isp ? -s  : s;
    float st = isp ? -tt : tt;
    v2f cv = {c, c};
    v2f sv = {ss, ss};
#pragma unroll
    for (int i = 0; i < 8; ++i) b[i] = b[i]*cv + pc[i]*sv;
    if (WV){
        v2f pv[8];
#pragma unroll
        for (int i = 0; i < 8; ++i){ pv[i].x = shuf<R>(v[i].x); pv[i].y = shuf<R>(v[i].y); }
#pragma unroll
        for (int i = 0; i < 8; ++i) v[i] = v[i]*cv + pv[i]*sv;
    }
    nrm = fmaf(st, gam, nrm);
}

template<bool WV>
__device__ __forceinline__ void jac_sweep(v2f* b, v2f* v, float &nrm, int t){
    // Interleave DPP rounds and DS rounds so both pipes stay fed.
    jac_round< 1,WV>(b,v,nrm,t); jac_round< 9,WV>(b,v,nrm,t);
    jac_round< 2,WV>(b,v,nrm,t); jac_round<10,WV>(b,v,nrm,t);
    jac_round< 3,WV>(b,v,nrm,t); jac_round<11,WV>(b,v,nrm,t);
    jac_round< 4,WV>(b,v,nrm,t); jac_round<12,WV>(b,v,nrm,t);
    jac_round< 5,WV>(b,v,nrm,t); jac_round<13,WV>(b,v,nrm,t);
    jac_round< 6,WV>(b,v,nrm,t); jac_round<14,WV>(b,v,nrm,t);
    jac_round< 7,WV>(b,v,nrm,t); jac_round< 8,WV>(b,v,nrm,t);
    jac_round<15,WV>(b,v,nrm,t);
}

// ---------------------------------------------------------------------------
// A: s = svd(W_sym) desc -> G[136] = triScale * diff_exp factor; WbT transpose.
__global__ __launch_bounds__(256) void k_prep(const float* __restrict__ W,
                                              const float* __restrict__ Wb,
                                              float* __restrict__ ws){
    __shared__ float sigv[16];
    __shared__ float s_srt[16];
    const int tid = threadIdx.x;
    const int t = tid & 15;
    if (tid < 64){
        v2f b[8]; float nrm = 0.f;
        float* bf = (float*)b;
#pragma unroll
        for (int i = 0; i < 16; ++i){
            float val = 0.5f * (W[i*16 + t] + W[t*16 + i]);
            bf[i] = val;
            nrm = fmaf(val, val, nrm);
        }
#pragma unroll 1
        for (int sw = 0; sw < NSWEEP_SMALL; ++sw) jac_sweep<false>(b, b, nrm, t);
        float n2 = 0.f;
#pragma unroll
        for (int i = 0; i < 16; ++i) n2 = fmaf(bf[i], bf[i], n2);
        float sig = sqrtf(n2);
        if (tid < 16) sigv[t] = sig;
    }
    __syncthreads();
    if (tid < 16){
        float sig = sigv[t];
        int rank = 0;
#pragma unroll
        for (int u = 0; u < 16; ++u){
            float su = sigv[u];
            rank += (su > sig || (su == sig && u < t)) ? 1 : 0;
        }
        s_srt[rank] = sig;   // descending, matches jnp.linalg.svd order
    }
    // transpose Wb [64][137] -> WbT [137][64]
    for (int e = tid; e < 8768; e += 256){
        int o = e / 137, i = e - o*137;
        ws[OFF_WBT + i*64 + o] = Wb[e];
    }
    __syncthreads();
    if (tid < 136){
        int r, c; tri_rc(tid, r, c);
        float sr = s_srt[r], sc = s_srt[c];
        float den = sr - sc;
        bool eq = fabsf(den) < EPSV;
        float er = expf(sr), ec = expf(sc);
        float num = eq ? 0.5f*(er + ec) : (er - ec);
        float dd  = eq ? 1.f : den;
        float scale = (r == c) ? 1.f : SQRT2F;
        ws[OFF_G + tid] = scale * num / dd;
    }
}

// ---------------------------------------------------------------------------
// B: per-matrix eigh + logm lower triangle + per-block mean partials.
//    16 lanes/matrix, 16 matrices/block. LDS 18.4 KB.
__global__ __launch_bounds__(256) void k_logm(const float* __restrict__ x,
                                              float* __restrict__ L,
                                              float* __restrict__ mpart){
    __shared__ float sm[4608];     // Bl[g][16][17] (4352) + cof[g][16] (256)
    float* Bl  = sm;               // g*272 + i*17 + t
    float* cof = sm + 4352;        // g*16 + j
    const int tid = threadIdx.x;
    const int t = tid & 15;
    const int g = tid >> 4;
    const size_t m = (size_t)blockIdx.x * 16 + g;
    const float* xp = x + m * 256;
    v2f b[8]; float nrm = 0.f;
    float* bf = (float*)b;
#pragma unroll
    for (int i = 0; i < 16; ++i){
        float val = xp[i*16 + t];
        bf[i] = val;
        nrm = fmaf(val, val, nrm);
    }
#pragma unroll 1
    for (int sw = 0; sw < NSWEEP_BIG; ++sw) jac_sweep<false>(b, b, nrm, t);
    // eigenvalue = ||b||, eigenvector = b/||b|| (SPD: eigs >= 0.5, clamp inert)
    float n2 = 0.f;
#pragma unroll
    for (int i = 0; i < 16; ++i) n2 = fmaf(bf[i], bf[i], n2);
    float lam = sqrtf(n2);
    float w = logf(fmaxf(lam, EPSV));
    float coef = w / n2;            // logm = sum_j coef_j b_j b_j^T
#pragma unroll
    for (int i = 0; i < 16; ++i) Bl[g*272 + i*17 + t] = bf[i];
    cof[g*16 + t] = coef;
    __syncthreads();
    float outv[9];
    float* Lp = L + m * 136;
#pragma unroll
    for (int k = 0; k < 9; ++k){
        int d = t + 16*k;
        float acc = 0.f;
        if (d < 136){
            int r, c; tri_rc(d, r, c);
#pragma unroll
            for (int j = 0; j < 16; ++j)
                acc = fmaf(cof[g*16 + j] * Bl[g*272 + r*17 + j], Bl[g*272 + c*17 + j], acc);
            Lp[d] = acc;
        }
        outv[k] = acc;
    }
    __syncthreads();                // all Bl reads done; alias as reduction buffer
    float* red = sm;                // red[g*144 + d]
#pragma unroll
    for (int k = 0; k < 9; ++k){
        int d = t + 16*k;
        red[g*144 + d] = outv[k];   // d in [0,144); zeros for d>=136
    }
    __syncthreads();
    if (tid < 136){
        float s = 0.f;
#pragma unroll
        for (int gg = 0; gg < 16; ++gg) s += red[gg*144 + tid];
        mpart[(size_t)blockIdx.x * 136 + tid] = s;
    }
}

// ---------------------------------------------------------------------------
// D: finalize mean (sum 200 block-partials), then xm = lower_triangle(sym_logm(mean)).
//    V tracked so the SIGNED eigenvalue (lam = v.b) feeds the EPS clamp.
__global__ __launch_bounds__(256) void k_xm(float* __restrict__ ws){
    __shared__ float Ms[136];
    __shared__ float Vl[16][20];
    __shared__ float Hl2[16][20];
    const int n = blockIdx.x;
    const int tid = threadIdx.x;
    if (tid < 136){
        const float* mp = ws + OFF_MPART + (size_t)n * 200 * 136 + tid;
        float s = 0.f;
#pragma unroll 4
        for (int c = 0; c < 200; ++c) s += mp[(size_t)c * 136];
        s *= (1.f/3200.f);
        ws[OFF_MEAN + n*136 + tid] = s;
        Ms[tid] = s;
    }
    __syncthreads();
    const int t = tid & 15;
    if (tid < 64){
        v2f b[8], v[8]; float nrm = 0.f;
        float* bf = (float*)b;
        float* vf = (float*)v;
#pragma unroll
        for (int i = 0; i < 16; ++i){
            int r = (i > t) ? i : t, c = (i > t) ? t : i;
            bf[i] = Ms[r*(r+1)/2 + c];
            vf[i] = (i == t) ? 1.f : 0.f;
            nrm = fmaf(bf[i], bf[i], nrm);
        }
#pragma unroll 1
        for (int sw = 0; sw < NSWEEP_SMALL; ++sw) jac_sweep<true>(b, v, nrm, t);
        float lam = 0.f;
#pragma unroll
        for (int i = 0; i < 16; ++i) lam = fmaf(vf[i], bf[i], lam);  // signed eig
        float w = logf(fmaxf(lam, EPSV));
        if (tid < 16){
#pragma unroll
            for (int i = 0; i < 16; ++i){ Vl[i][t] = vf[i]; Hl2[i][t] = w * vf[i]; }
        }
    }
    __syncthreads();
    if (tid < 16){
        for (int k = 0; k < 9; ++k){
            int d = t + 16*k;
            if (d < 136){
                int r, c; tri_rc(d, r, c);
                float acc = 0.f;
#pragma unroll
                for (int j = 0; j < 16; ++j) acc = fmaf(Hl2[r][j], Vl[c][j], acc);
                float scale = (r == c) ? 1.f : SQRT2F;
                ws[OFF_XM + n*136 + d] = scale * acc;
            }
        }
    }
}

// ---------------------------------------------------------------------------
// E: partial covariance. xc = G*(L - mean). 512 threads, one 8x4 tile/thread.
__global__ __launch_bounds__(512) void k_cov(float* __restrict__ ws){
    __shared__ __align__(16) float xc[8][136];
    __shared__ __align__(16) float Gl[136];
    __shared__ __align__(16) float Ml[136];
    const int bid = blockIdx.x;
    const int n = bid & 31, c8 = bid >> 5;   // c8 in 0..7, 400 p each
    const int tid = threadIdx.x;
    if (tid < 136){
        Gl[tid] = ws[OFF_G + tid];
        Ml[tid] = ws[OFF_MEAN + n*136 + tid];
    }
    int bi = 0, bj = 0; const bool val = (tid < 306);
    if (val){
        int T = tid;
        int bb = (int)floorf((sqrtf(fmaf(4.f, (float)T, 1.f)) - 1.f) * 0.5f);
        while (bb*bb + bb > T) bb--;
        while ((bb+1)*(bb+1) + (bb+1) <= T) bb++;
        bi = bb; bj = T - bb*bb - bb;
    }
    float a0[32];
#pragma unroll
    for (int i = 0; i < 32; ++i) a0[i] = 0.f;
    const float* Lbase = ws + OFF_L + (size_t)n * 3200 * 136;
    for (int st = 0; st < 50; ++st){
        __syncthreads();
        int p0 = c8*400 + st*8;
        if (tid < 272){
            int pp = tid / 34, dd = tid - pp*34;
            float4 lv = *(const float4*)(Lbase + (size_t)(p0+pp)*136 + dd*4);
            float4 gv = *(const float4*)(&Gl[dd*4]);
            float4 mv = *(const float4*)(&Ml[dd*4]);
            float4 r;
            r.x = (lv.x - mv.x) * gv.x; r.y = (lv.y - mv.y) * gv.y;
            r.z = (lv.z - mv.z) * gv.z; r.w = (lv.w - mv.w) * gv.w;
            *(float4*)(&xc[pp][dd*4]) = r;
        }
        __syncthreads();
        if (val){
#pragma unroll 1
            for (int pp = 0; pp < 8; ++pp){
                const float4 u0 = *(const float4*)(&xc[pp][bi*8]);
                const float4 u1 = *(const float4*)(&xc[pp][bi*8+4]);
                const float4 w4 = *(const float4*)(&xc[pp][bj*4]);
                float ui[8] = {u0.x,u0.y,u0.z,u0.w,u1.x,u1.y,u1.z,u1.w};
                float wj[4] = {w4.x,w4.y,w4.z,w4.w};
#pragma unroll
                for (int di = 0; di < 8; ++di)
#pragma unroll
                    for (int dj = 0; dj < 4; ++dj)
                        a0[di*4+dj] = fmaf(ui[di], wj[dj], a0[di*4+dj]);
            }
        }
    }
    if (val){
        float* part = ws + OFF_PART + ((size_t)c8*32 + n)*9316;
#pragma unroll
        for (int di = 0; di < 8; ++di){
            int i = bi*8 + di;
#pragma unroll
            for (int dj = 0; dj < 4; ++dj){
                int j = bj*4 + dj;
                if (j <= i) part[i*(i+1)/2 + j] = a0[di*4+dj];
            }
        }
    }
}

// ---------------------------------------------------------------------------
// F1: sum partials -> cov -> Cholesky (tri-packed LDS) -> trace -> Tout = outM*WbT
__global__ __launch_bounds__(256) void k_chol(float* __restrict__ ws){
    __shared__ float T[9316];
    __shared__ float xr[137];
    __shared__ float trs[2];
    const int n = blockIdx.x;
    const int tid = threadIdx.x;
    for (int e = tid; e < 9316; e += 256){
        float s = 0.f;
#pragma unroll
        for (int c = 0; c < 8; ++c) s += ws[OFF_PART + ((size_t)c*32 + n)*9316 + e];
        T[e] = s * (1.f/3199.f);
    }
    if (tid < 136) xr[tid] = ws[OFF_XM + n*136 + tid];
    __syncthreads();
    for (int k = 0; k < 136; ++k){
        const int kb = k*(k+1)/2;
        float dkk = T[kb + k];
        float d = sqrtf(dkk);
        float rinv = 1.f / d;
        __syncthreads();
        for (int i = k+1+tid; i < 136; i += 256) T[i*(i+1)/2 + k] *= rinv;
        if (tid == 0) T[kb + k] = d;
        __syncthreads();
        const int m = 135 - k;
        const int cnt = m*(m+1)/2;
        const int Lc = (cnt + 255) >> 8;
        int e0 = tid * Lc, e1 = e0 + Lc; if (e1 > cnt) e1 = cnt;
        if (e0 < e1){
            float A = 2.f*m + 1.f;
            int jp = (int)floorf((A - sqrtf(fmaf(A, A, -8.f*e0))) * 0.5f);
            if (jp < 0) jp = 0;
            while (jp > 0 && jp*m - jp*(jp-1)/2 > e0) jp--;
            while ((jp+1)*m - (jp+1)*jp/2 <= e0) jp++;
            int ip = jp + (e0 - (jp*m - jp*(jp-1)/2));
            int i = k+1+ip, j = k+1+jp;
            int bI = i*(i+1)/2;
            int idx_ij = bI + j, idx_ik = bI + k;
            float cj = T[j*(j+1)/2 + k];
            for (int e = e0; e < e1; ++e){
                T[idx_ij] -= T[idx_ik] * cj;
                i++;
                if (i == 136){
                    j++; i = j;
                    int bb = i*(i+1)/2;
                    idx_ij = bb + j; idx_ik = bb + k;
                    cj = T[idx_ik];
                } else {
                    idx_ij += i; idx_ik += i;
                }
            }
        }
        __syncthreads();
    }
    if (tid == 0){
        float tr = 1.f;
        for (int kk = 0; kk < 136; ++kk) tr += T[kk*(kk+1)/2 + kk];
        trs[0] = tr; trs[1] = 1.f / tr;
    }
    __syncthreads();
    const float tr = trs[0], itr = trs[1];
    const float c6 = tr * 1e-6f;
    const float* WbT = ws + OFF_WBT;
    float* Tout = ws + OFF_T + (size_t)n * 8768;
    const int q = tid & 63, wv = tid >> 6;
    for (int i = wv; i <= 136; i += 4){
        float accv;
        if (i < 136){
            const int ib = i*(i+1)/2;
            float acc = 0.f;
            for (int j = 0; j <= i; ++j) acc = fmaf(T[ib + j], WbT[j*64 + q], acc);
            accv = fmaf(c6, WbT[i*64 + q], itr * acc);
        } else {
            float acc = WbT[136*64 + q];               // out[D][D] = 1
            for (int j = 0; j < 136; ++j) acc = fmaf(xr[j], WbT[j*64 + q], acc);
            accv = fmaf(c6, WbT[136*64 + q], itr * acc);
        }
        Tout[i*64 + q] = accv;
    }
}

// ---------------------------------------------------------------------------
// F2: res[n] = Wb @ Tout[n]  -> d_out [32][64][64]. Tout staged in LDS.
__global__ __launch_bounds__(256) void k_bimap(const float* __restrict__ ws,
                                               const float* __restrict__ Wb,
                                               float* __restrict__ out){
    __shared__ float Tl[8768];
    const int n = blockIdx.x;
    const int tid = threadIdx.x;
    const float* Tn = ws + OFF_T + (size_t)n * 8768;
    for (int e = tid; e < 8768; e += 256) Tl[e] = Tn[e];
    __syncthreads();
    const int q = tid & 63, ob = tid >> 6;
#pragma unroll 1
    for (int o = ob; o < 64; o += 4){
        float acc = 0.f;
        const float* wr = Wb + o*137;
        for (int i = 0; i < 137; ++i) acc = fmaf(wr[i], Tl[i*64 + q], acc);
        out[(size_t)n*4096 + o*64 + q] = acc;
    }
}

// ---------------------------------------------------------------------------
extern "C" void kernel_launch(void* const* d_in, const int* in_sizes, int n_in,
                              void* d_out, int out_size, void* d_ws, size_t ws_size,
                              hipStream_t stream){
    const float* x   = (const float*)d_in[0];
    const float* W   = (const float*)d_in[1];
    const float* Wb  = (const float*)d_in[2];
    float* out = (float*)d_out;
    float* ws  = (float*)d_ws;

    k_prep <<<   1, 256, 0, stream>>>(W, Wb, ws);
    k_logm <<<6400, 256, 0, stream>>>(x, ws + OFF_L, ws + OFF_MPART);
    k_xm   <<<  32, 256, 0, stream>>>(ws);
    k_cov  <<< 256, 512, 0, stream>>>(ws);
    k_chol <<<  32, 256, 0, stream>>>(ws);
    k_bimap<<<  32, 256, 0, stream>>>(ws, Wb, out);
}

// Round 5
// 1031.140 us; speedup vs baseline: 1.2270x; 1.0950x over previous
//
#include <hip/hip_runtime.h>
#include <math.h>

// ---------------------------------------------------------------------------
// RiemannianPooling: logm(eigh) -> mean -> diff_exp -> cov -> cholesky -> bimap
// N=32, M*T*V=3200, C=16, D=136, out 32x64x64 fp32.
// R5: == R4 (dual-matrix Jacobi ILP, fused prep/xm/bimap, 4 launches) with
//     k_xm_mean thread-coverage bug fixed (was tid<272 with 256 threads ->
//     mean dims 120..135 lost half their partials).
// ---------------------------------------------------------------------------

#define EPSV 1e-4f
#define NSWEEP_BIG 8
#define NSWEEP_SMALL 10
#define SQRT2F 1.41421356237309515f

// workspace layout (float offsets) — total 66.5 MB
#define OFF_G      0            // 136
#define OFF_WBT    160          // 137*64 = 8768
#define OFF_MEAN   8960         // 32*136
#define OFF_XM     13312        // 32*136
#define OFF_MPART  320000       // 3200*136 = 435200 (aliases head of PART)
#define OFF_PART   320000       // 8*32*9316 = 2384896 (written after MPART consumed)
#define OFF_L      2704896      // 102400*136

typedef float v2f __attribute__((ext_vector_type(2)));

__device__ __forceinline__ float rcp_f(float x){ return __builtin_amdgcn_rcpf(x); }
__device__ __forceinline__ float rsq_f(float x){ return __builtin_amdgcn_rsqf(x); }

// XOR within 16-lane rows via DPP (VALU pipe). Single-instr: 1,2,3 quad_perm;
// 7 row_half_mirror; 8 row_ror:8; 15 row_mirror. 4,5,6 compose with 7.
template<int R>
__device__ __forceinline__ float xl(float x){
    int s = __float_as_int(x);
    if constexpr (R == 1){
        return __int_as_float(__builtin_amdgcn_update_dpp(s, s, 0xB1, 0xF, 0xF, false));
    } else if constexpr (R == 2){
        return __int_as_float(__builtin_amdgcn_update_dpp(s, s, 0x4E, 0xF, 0xF, false));
    } else if constexpr (R == 3){
        return __int_as_float(__builtin_amdgcn_update_dpp(s, s, 0x1B, 0xF, 0xF, false));
    } else if constexpr (R == 7){
        return __int_as_float(__builtin_amdgcn_update_dpp(s, s, 0x141, 0xF, 0xF, false));
    } else if constexpr (R == 8){
        return __int_as_float(__builtin_amdgcn_update_dpp(s, s, 0x128, 0xF, 0xF, false));
    } else if constexpr (R == 15){
        return __int_as_float(__builtin_amdgcn_update_dpp(s, s, 0x140, 0xF, 0xF, false));
    } else {                                // 4,5,6 = (R^7) then 7
        return xl<7>(xl<R^7>(x));
    }
}

// Pipe-splitting shuffle: masks 9..14 on the DS crossbar, rest on VALU DPP.
template<int R>
__device__ __forceinline__ float shuf(float x){
    if constexpr (R >= 9 && R <= 14){
        constexpr int IMM = (R << 10) | 0x1F;   // BitMode: xor=R, and=0x1F
        return __int_as_float(__builtin_amdgcn_ds_swizzle(__float_as_int(x), IMM));
    } else {
        return xl<R>(x);
    }
}

// decode linear lower-tri index d -> (r,c), d = r(r+1)/2 + c
__device__ __forceinline__ void tri_rc(int d, int &r, int &c){
    int rr = (int)floorf((sqrtf(fmaf(8.f, (float)d, 1.f)) - 1.f) * 0.5f);
    if (rr*(rr+1)/2 > d) rr--;
    if ((rr+1)*(rr+2)/2 <= d) rr++;
    r = rr; c = d - rr*(rr+1)/2;
}

// ---- single-matrix Jacobi round (for prep & xm) ---------------------------
template<int R, bool WV>
__device__ __forceinline__ void jac_round(v2f* b, v2f* v, float &nrm, int t){
    v2f pc[8];
#pragma unroll
    for (int i = 0; i < 8; ++i){ pc[i].x = shuf<R>(b[i].x); pc[i].y = shuf<R>(b[i].y); }
    float pn = shuf<R>(nrm);
    v2f g2 = {0.f, 0.f};
#pragma unroll
    for (int i = 0; i < 8; ++i) g2 = g2 + b[i]*pc[i];
    float gam = g2.x + g2.y;
    constexpr int HB = (R & 8) ? 8 : ((R & 4) ? 4 : ((R & 2) ? 2 : 1));
    const bool isp = ((t & HB) == 0);
    float alpha = isp ? nrm : pn;
    float beta  = isp ? pn  : nrm;
    float zeta = (beta - alpha) * 0.5f * rcp_f(gam);
    float tt = copysignf(rcp_f(fabsf(zeta) + sqrtf(fmaf(zeta, zeta, 1.f))), zeta);
    tt = (gam == 0.f) ? 0.f : tt;
    float c = rsq_f(fmaf(tt, tt, 1.f));
    float s = tt * c;
    float ss = isp ? -s  : s;
    float st = isp ? -tt : tt;
    v2f cv = {c, c};
    v2f sv = {ss, ss};
#pragma unroll
    for (int i = 0; i < 8; ++i) b[i] = b[i]*cv + pc[i]*sv;
    if (WV){
        v2f pv[8];
#pragma unroll
        for (int i = 0; i < 8; ++i){ pv[i].x = shuf<R>(v[i].x); pv[i].y = shuf<R>(v[i].y); }
#pragma unroll
        for (int i = 0; i < 8; ++i) v[i] = v[i]*cv + pv[i]*sv;
    }
    nrm = fmaf(st, gam, nrm);
}

template<bool WV>
__device__ __forceinline__ void jac_sweep(v2f* b, v2f* v, float &nrm, int t){
    jac_round< 1,WV>(b,v,nrm,t); jac_round< 9,WV>(b,v,nrm,t);
    jac_round< 2,WV>(b,v,nrm,t); jac_round<10,WV>(b,v,nrm,t);
    jac_round< 3,WV>(b,v,nrm,t); jac_round<11,WV>(b,v,nrm,t);
    jac_round< 4,WV>(b,v,nrm,t); jac_round<12,WV>(b,v,nrm,t);
    jac_round< 5,WV>(b,v,nrm,t); jac_round<13,WV>(b,v,nrm,t);
    jac_round< 6,WV>(b,v,nrm,t); jac_round<14,WV>(b,v,nrm,t);
    jac_round< 7,WV>(b,v,nrm,t); jac_round< 8,WV>(b,v,nrm,t);
    jac_round<15,WV>(b,v,nrm,t);
}

// ---- dual-matrix Jacobi round (2 independent chains per lane) -------------
template<int R>
__device__ __forceinline__ void jac_round2(v2f* b0, v2f* b1, float &nrm0, float &nrm1, int t){
    v2f p0[8], p1[8];
#pragma unroll
    for (int i = 0; i < 8; ++i){
        p0[i].x = shuf<R>(b0[i].x); p0[i].y = shuf<R>(b0[i].y);
        p1[i].x = shuf<R>(b1[i].x); p1[i].y = shuf<R>(b1[i].y);
    }
    float q0 = shuf<R>(nrm0), q1 = shuf<R>(nrm1);
    v2f g20 = {0.f,0.f}, g21 = {0.f,0.f};
#pragma unroll
    for (int i = 0; i < 8; ++i){ g20 = g20 + b0[i]*p0[i]; g21 = g21 + b1[i]*p1[i]; }
    float gam0 = g20.x + g20.y, gam1 = g21.x + g21.y;
    constexpr int HB = (R & 8) ? 8 : ((R & 4) ? 4 : ((R & 2) ? 2 : 1));
    const bool isp = ((t & HB) == 0);
    float al0 = isp ? nrm0 : q0,  be0 = isp ? q0 : nrm0;
    float al1 = isp ? nrm1 : q1,  be1 = isp ? q1 : nrm1;
    float ze0 = (be0 - al0) * 0.5f * rcp_f(gam0);
    float ze1 = (be1 - al1) * 0.5f * rcp_f(gam1);
    float tt0 = copysignf(rcp_f(fabsf(ze0) + sqrtf(fmaf(ze0, ze0, 1.f))), ze0);
    float tt1 = copysignf(rcp_f(fabsf(ze1) + sqrtf(fmaf(ze1, ze1, 1.f))), ze1);
    tt0 = (gam0 == 0.f) ? 0.f : tt0;
    tt1 = (gam1 == 0.f) ? 0.f : tt1;
    float c0 = rsq_f(fmaf(tt0, tt0, 1.f));
    float c1 = rsq_f(fmaf(tt1, tt1, 1.f));
    float s0 = tt0 * c0, s1 = tt1 * c1;
    float ss0 = isp ? -s0  : s0,  st0 = isp ? -tt0 : tt0;
    float ss1 = isp ? -s1  : s1,  st1 = isp ? -tt1 : tt1;
    v2f cv0 = {c0,c0}, sv0 = {ss0,ss0};
    v2f cv1 = {c1,c1}, sv1 = {ss1,ss1};
#pragma unroll
    for (int i = 0; i < 8; ++i){
        b0[i] = b0[i]*cv0 + p0[i]*sv0;
        b1[i] = b1[i]*cv1 + p1[i]*sv1;
    }
    nrm0 = fmaf(st0, gam0, nrm0);
    nrm1 = fmaf(st1, gam1, nrm1);
}

__device__ __forceinline__ void jac_sweep2(v2f* b0, v2f* b1, float &n0, float &n1, int t){
    jac_round2< 1>(b0,b1,n0,n1,t); jac_round2< 9>(b0,b1,n0,n1,t);
    jac_round2< 2>(b0,b1,n0,n1,t); jac_round2<10>(b0,b1,n0,n1,t);
    jac_round2< 3>(b0,b1,n0,n1,t); jac_round2<11>(b0,b1,n0,n1,t);
    jac_round2< 4>(b0,b1,n0,n1,t); jac_round2<12>(b0,b1,n0,n1,t);
    jac_round2< 5>(b0,b1,n0,n1,t); jac_round2<13>(b0,b1,n0,n1,t);
    jac_round2< 6>(b0,b1,n0,n1,t); jac_round2<14>(b0,b1,n0,n1,t);
    jac_round2< 7>(b0,b1,n0,n1,t); jac_round2< 8>(b0,b1,n0,n1,t);
    jac_round2<15>(b0,b1,n0,n1,t);
}

// ---------------------------------------------------------------------------
// B: per-matrix eigh + logm lower triangle + per-block mean partials.
//    2 matrices per 16-lane group, 32 matrices/block, 3200 matrix-blocks.
//    Block 3200 = prep (W svd -> G; Wb transpose) hidden under the others.
__global__ __launch_bounds__(256) void k_logm(const float* __restrict__ x,
                                              float* __restrict__ L,
                                              float* __restrict__ mpart,
                                              const float* __restrict__ W,
                                              const float* __restrict__ Wb,
                                              float* __restrict__ ws){
    __shared__ float sm[4608];     // Bl[16][272] + cof[16][16]  (18.4 KB)
    const int tid = threadIdx.x;
    const int t = tid & 15;
    const int g = tid >> 4;
    if (blockIdx.x == 3200){
        // ---- prep: s = svd(W_sym) desc -> G; WbT transpose ----
        float* sigv  = sm;          // 16
        float* s_srt = sm + 16;     // 16
        if (tid < 64){
            v2f b[8]; float nrm = 0.f;
            float* bf = (float*)b;
#pragma unroll
            for (int i = 0; i < 16; ++i){
                float val = 0.5f * (W[i*16 + t] + W[t*16 + i]);
                bf[i] = val;
                nrm = fmaf(val, val, nrm);
            }
#pragma unroll 1
            for (int sw = 0; sw < NSWEEP_SMALL; ++sw) jac_sweep<false>(b, b, nrm, t);
            float n2 = 0.f;
#pragma unroll
            for (int i = 0; i < 16; ++i) n2 = fmaf(bf[i], bf[i], n2);
            float sig = sqrtf(n2);
            if (tid < 16) sigv[t] = sig;
        }
        __syncthreads();
        if (tid < 16){
            float sig = sigv[t];
            int rank = 0;
#pragma unroll
            for (int u = 0; u < 16; ++u){
                float su = sigv[u];
                rank += (su > sig || (su == sig && u < t)) ? 1 : 0;
            }
            s_srt[rank] = sig;   // descending, matches jnp.linalg.svd order
        }
        for (int e = tid; e < 8768; e += 256){
            int o = e / 137, i = e - o*137;
            ws[OFF_WBT + i*64 + o] = Wb[e];
        }
        __syncthreads();
        if (tid < 136){
            int r, c; tri_rc(tid, r, c);
            float sr = s_srt[r], sc = s_srt[c];
            float den = sr - sc;
            bool eq = fabsf(den) < EPSV;
            float er = expf(sr), ec = expf(sc);
            float num = eq ? 0.5f*(er + ec) : (er - ec);
            float dd  = eq ? 1.f : den;
            float scale = (r == c) ? 1.f : SQRT2F;
            ws[OFF_G + tid] = scale * num / dd;
        }
        return;
    }
    // ---- main: 2 matrices per group ----
    const size_t m0 = (size_t)blockIdx.x * 32 + g * 2;
    const float* xp0 = x + m0 * 256;
    v2f b0[8], b1[8]; float nrm0 = 0.f, nrm1 = 0.f;
    float* bf0 = (float*)b0;
    float* bf1 = (float*)b1;
#pragma unroll
    for (int i = 0; i < 16; ++i){
        float v0 = xp0[i*16 + t];
        float v1 = xp0[256 + i*16 + t];
        bf0[i] = v0; bf1[i] = v1;
        nrm0 = fmaf(v0, v0, nrm0);
        nrm1 = fmaf(v1, v1, nrm1);
    }
#pragma unroll 1
    for (int sw = 0; sw < NSWEEP_BIG; ++sw) jac_sweep2(b0, b1, nrm0, nrm1, t);
    // eigenvalue = ||b||, eigenvector = b/||b|| (SPD: eigs >= 0.5, clamp inert)
    float n20 = 0.f, n21 = 0.f;
#pragma unroll
    for (int i = 0; i < 16; ++i){ n20 = fmaf(bf0[i], bf0[i], n20); n21 = fmaf(bf1[i], bf1[i], n21); }
    float w0 = logf(fmaxf(sqrtf(n20), EPSV));
    float w1 = logf(fmaxf(sqrtf(n21), EPSV));
    float coef0 = w0 / n20;         // logm = sum_j coef_j b_j b_j^T
    float coef1 = w1 / n21;
    int rr[9], cc[9];
#pragma unroll
    for (int k = 0; k < 9; ++k){
        int d = t + 16*k;
        if (d < 136) tri_rc(d, rr[k], cc[k]); else { rr[k] = 0; cc[k] = 0; }
    }
    float* Bl  = sm;               // g*272 + i*17 + t
    float* cof = sm + 4352;        // g*16 + j
    float outv[9];
    // phase A: matrix m0
#pragma unroll
    for (int i = 0; i < 16; ++i) Bl[g*272 + i*17 + t] = bf0[i];
    cof[g*16 + t] = coef0;
    __syncthreads();
    {
        float* Lp = L + m0 * 136;
#pragma unroll
        for (int k = 0; k < 9; ++k){
            int d = t + 16*k;
            float acc = 0.f;
            if (d < 136){
#pragma unroll
                for (int j = 0; j < 16; ++j)
                    acc = fmaf(cof[g*16 + j] * Bl[g*272 + rr[k]*17 + j], Bl[g*272 + cc[k]*17 + j], acc);
                Lp[d] = acc;
            }
            outv[k] = acc;
        }
    }
    __syncthreads();
    // phase B: matrix m0+1
#pragma unroll
    for (int i = 0; i < 16; ++i) Bl[g*272 + i*17 + t] = bf1[i];
    cof[g*16 + t] = coef1;
    __syncthreads();
    {
        float* Lp = L + (m0 + 1) * 136;
#pragma unroll
        for (int k = 0; k < 9; ++k){
            int d = t + 16*k;
            float acc = 0.f;
            if (d < 136){
#pragma unroll
                for (int j = 0; j < 16; ++j)
                    acc = fmaf(cof[g*16 + j] * Bl[g*272 + rr[k]*17 + j], Bl[g*272 + cc[k]*17 + j], acc);
                Lp[d] = acc;
            }
            outv[k] += acc;
        }
    }
    __syncthreads();                // Bl reads done; alias as reduction buffer
    float* red = sm;                // red[g*144 + d]
#pragma unroll
    for (int k = 0; k < 9; ++k){
        int d = t + 16*k;
        red[g*144 + d] = outv[k];   // zeros for d>=136
    }
    __syncthreads();
    if (tid < 136){
        float s = 0.f;
#pragma unroll
        for (int gg = 0; gg < 16; ++gg) s += red[gg*144 + tid];
        mpart[(size_t)blockIdx.x * 136 + tid] = s;
    }
}

// ---------------------------------------------------------------------------
// C: finalize mean from 100 block-partials per n. 136 active threads, full
//    coverage (R4 bug: tid<272 with 256 threads lost dims 120..135).
__global__ __launch_bounds__(256) void k_xm_mean(float* __restrict__ ws){
    const int n = blockIdx.x;
    const int tid = threadIdx.x;
    if (tid < 136){
        const float* mp = ws + OFF_MPART + (size_t)n * 100 * 136 + tid;
        float s = 0.f;
#pragma unroll 4
        for (int c = 0; c < 100; ++c) s += mp[(size_t)c * 136];
        ws[OFF_MEAN + n*136 + tid] = s * (1.f/3200.f);
    }
}

// ---------------------------------------------------------------------------
// E: blocks 0..255: partial covariance (xc = G*(L-mean), 8x4 tiles).
//    blocks 256..287: xm = lower_triangle(sym_logm(mean)) — hidden under cov.
__global__ __launch_bounds__(512) void k_cov(float* __restrict__ ws){
    __shared__ __align__(16) float xc[8][136];
    __shared__ __align__(16) float Gl[136];
    __shared__ __align__(16) float Ml[136];
    const int bid = blockIdx.x;
    const int tid = threadIdx.x;
    if (bid >= 256){
        // ---- xm for n = bid-256 (V tracked; SIGNED eigenvalue feeds clamp) ----
        const int n = bid - 256;
        float* smf = &xc[0][0];        // 1088 floats scratch
        float* Ms  = smf;              // 136
        float* Vl  = smf + 144;        // 16*20
        float* Hl2 = smf + 464;        // 16*20
        if (tid < 136) Ms[tid] = ws[OFF_MEAN + n*136 + tid];
        __syncthreads();
        const int t = tid & 15;
        if (tid < 64){
            v2f b[8], v[8]; float nrm = 0.f;
            float* bf = (float*)b;
            float* vf = (float*)v;
#pragma unroll
            for (int i = 0; i < 16; ++i){
                int r = (i > t) ? i : t, c = (i > t) ? t : i;
                bf[i] = Ms[r*(r+1)/2 + c];
                vf[i] = (i == t) ? 1.f : 0.f;
                nrm = fmaf(bf[i], bf[i], nrm);
            }
#pragma unroll 1
            for (int sw = 0; sw < NSWEEP_SMALL; ++sw) jac_sweep<true>(b, v, nrm, t);
            float lam = 0.f;
#pragma unroll
            for (int i = 0; i < 16; ++i) lam = fmaf(vf[i], bf[i], lam);  // signed
            float w = logf(fmaxf(lam, EPSV));
            if (tid < 16){
#pragma unroll
                for (int i = 0; i < 16; ++i){ Vl[i*20 + t] = vf[i]; Hl2[i*20 + t] = w * vf[i]; }
            }
        }
        __syncthreads();
        if (tid < 16){
            for (int k = 0; k < 9; ++k){
                int d = t + 16*k;
                if (d < 136){
                    int r, c; tri_rc(d, r, c);
                    float acc = 0.f;
#pragma unroll
                    for (int j = 0; j < 16; ++j) acc = fmaf(Hl2[r*20 + j], Vl[c*20 + j], acc);
                    float scale = (r == c) ? 1.f : SQRT2F;
                    ws[OFF_XM + n*136 + d] = scale * acc;
                }
            }
        }
        return;
    }
    // ---- cov partials ----
    const int n = bid & 31, c8 = bid >> 5;   // c8 in 0..7, 400 p each
    if (tid < 136){
        Gl[tid] = ws[OFF_G + tid];
        Ml[tid] = ws[OFF_MEAN + n*136 + tid];
    }
    int bi = 0, bj = 0; const bool val = (tid < 306);
    if (val){
        int T = tid;
        int bb = (int)floorf((sqrtf(fmaf(4.f, (float)T, 1.f)) - 1.f) * 0.5f);
        while (bb*bb + bb > T) bb--;
        while ((bb+1)*(bb+1) + (bb+1) <= T) bb++;
        bi = bb; bj = T - bb*bb - bb;
    }
    float a0[32];
#pragma unroll
    for (int i = 0; i < 32; ++i) a0[i] = 0.f;
    const float* Lbase = ws + OFF_L + (size_t)n * 3200 * 136;
    for (int st = 0; st < 50; ++st){
        __syncthreads();
        int p0 = c8*400 + st*8;
        if (tid < 272){
            int pp = tid / 34, dd = tid - pp*34;
            float4 lv = *(const float4*)(Lbase + (size_t)(p0+pp)*136 + dd*4);
            float4 gv = *(const float4*)(&Gl[dd*4]);
            float4 mv = *(const float4*)(&Ml[dd*4]);
            float4 r;
            r.x = (lv.x - mv.x) * gv.x; r.y = (lv.y - mv.y) * gv.y;
            r.z = (lv.z - mv.z) * gv.z; r.w = (lv.w - mv.w) * gv.w;
            *(float4*)(&xc[pp][dd*4]) = r;
        }
        __syncthreads();
        if (val){
#pragma unroll 1
            for (int pp = 0; pp < 8; ++pp){
                const float4 u0 = *(const float4*)(&xc[pp][bi*8]);
                const float4 u1 = *(const float4*)(&xc[pp][bi*8+4]);
                const float4 w4 = *(const float4*)(&xc[pp][bj*4]);
                float ui[8] = {u0.x,u0.y,u0.z,u0.w,u1.x,u1.y,u1.z,u1.w};
                float wj[4] = {w4.x,w4.y,w4.z,w4.w};
#pragma unroll
                for (int di = 0; di < 8; ++di)
#pragma unroll
                    for (int dj = 0; dj < 4; ++dj)
                        a0[di*4+dj] = fmaf(ui[di], wj[dj], a0[di*4+dj]);
            }
        }
    }
    if (val){
        float* part = ws + OFF_PART + ((size_t)c8*32 + n)*9316;
#pragma unroll
        for (int di = 0; di < 8; ++di){
            int i = bi*8 + di;
#pragma unroll
            for (int dj = 0; dj < 4; ++dj){
                int j = bj*4 + dj;
                if (j <= i) part[i*(i+1)/2 + j] = a0[di*4+dj];
            }
        }
    }
}

// ---------------------------------------------------------------------------
// F: sum partials -> cov -> Cholesky (tri-packed LDS) -> trace -> Tout (LDS)
//    -> out = Wb @ Tout  (bimap fused; no global Tout round-trip).
__global__ __launch_bounds__(256) void k_chol(float* __restrict__ ws,
                                              const float* __restrict__ Wb,
                                              float* __restrict__ out){
    __shared__ float T[9316];
    __shared__ float xr[137];
    __shared__ float trs[2];
    __shared__ float ToutL[8768];
    const int n = blockIdx.x;
    const int tid = threadIdx.x;
    for (int e = tid; e < 9316; e += 256){
        float s = 0.f;
#pragma unroll
        for (int c = 0; c < 8; ++c) s += ws[OFF_PART + ((size_t)c*32 + n)*9316 + e];
        T[e] = s * (1.f/3199.f);
    }
    if (tid < 136) xr[tid] = ws[OFF_XM + n*136 + tid];
    __syncthreads();
    for (int k = 0; k < 136; ++k){
        const int kb = k*(k+1)/2;
        float dkk = T[kb + k];
        float d = sqrtf(dkk);
        float rinv = 1.f / d;
        __syncthreads();
        for (int i = k+1+tid; i < 136; i += 256) T[i*(i+1)/2 + k] *= rinv;
        if (tid == 0) T[kb + k] = d;
        __syncthreads();
        const int m = 135 - k;
        const int cnt = m*(m+1)/2;
        const int Lc = (cnt + 255) >> 8;
        int e0 = tid * Lc, e1 = e0 + Lc; if (e1 > cnt) e1 = cnt;
        if (e0 < e1){
            float A = 2.f*m + 1.f;
            int jp = (int)floorf((A - sqrtf(fmaf(A, A, -8.f*e0))) * 0.5f);
            if (jp < 0) jp = 0;
            while (jp > 0 && jp*m - jp*(jp-1)/2 > e0) jp--;
            while ((jp+1)*m - (jp+1)*jp/2 <= e0) jp++;
            int ip = jp + (e0 - (jp*m - jp*(jp-1)/2));
            int i = k+1+ip, j = k+1+jp;
            int bI = i*(i+1)/2;
            int idx_ij = bI + j, idx_ik = bI + k;
            float cj = T[j*(j+1)/2 + k];
            for (int e = e0; e < e1; ++e){
                T[idx_ij] -= T[idx_ik] * cj;
                i++;
                if (i == 136){
                    j++; i = j;
                    int bb = i*(i+1)/2;
                    idx_ij = bb + j; idx_ik = bb + k;
                    cj = T[idx_ik];
                } else {
                    idx_ij += i; idx_ik += i;
                }
            }
        }
        __syncthreads();
    }
    if (tid == 0){
        float tr = 1.f;
        for (int kk = 0; kk < 136; ++kk) tr += T[kk*(kk+1)/2 + kk];
        trs[0] = tr; trs[1] = 1.f / tr;
    }
    __syncthreads();
    const float tr = trs[0], itr = trs[1];
    const float c6 = tr * 1e-6f;
    const float* WbT = ws + OFF_WBT;
    const int q = tid & 63, wv = tid >> 6;
    for (int i = wv; i <= 136; i += 4){
        float accv;
        if (i < 136){
            const int ib = i*(i+1)/2;
            float acc = 0.f;
            for (int j = 0; j <= i; ++j) acc = fmaf(T[ib + j], WbT[j*64 + q], acc);
            accv = fmaf(c6, WbT[i*64 + q], itr * acc);
        } else {
            float acc = WbT[136*64 + q];               // out[D][D] = 1
            for (int j = 0; j < 136; ++j) acc = fmaf(xr[j], WbT[j*64 + q], acc);
            accv = fmaf(c6, WbT[136*64 + q], itr * acc);
        }
        ToutL[i*64 + q] = accv;
    }
    __syncthreads();
    // bimap: out[n][o][q] = sum_i Wb[o][i] * ToutL[i][q]
#pragma unroll 1
    for (int o = wv; o < 64; o += 4){
        float acc = 0.f;
        const float* wr = Wb + o*137;
        for (int i = 0; i < 137; ++i) acc = fmaf(wr[i], ToutL[i*64 + q], acc);
        out[(size_t)n*4096 + o*64 + q] = acc;
    }
}

// ---------------------------------------------------------------------------
extern "C" void kernel_launch(void* const* d_in, const int* in_sizes, int n_in,
                              void* d_out, int out_size, void* d_ws, size_t ws_size,
                              hipStream_t stream){
    const float* x   = (const float*)d_in[0];
    const float* W   = (const float*)d_in[1];
    const float* Wb  = (const float*)d_in[2];
    float* out = (float*)d_out;
    float* ws  = (float*)d_ws;

    k_logm   <<<3201, 256, 0, stream>>>(x, ws + OFF_L, ws + OFF_MPART, W, Wb, ws);
    k_xm_mean<<<  32, 256, 0, stream>>>(ws);
    k_cov    <<< 288, 512, 0, stream>>>(ws);
    k_chol   <<<  32, 256, 0, stream>>>(ws, Wb, out);
}

// Round 6
// 870.724 us; speedup vs baseline: 1.4530x; 1.1842x over previous
//
#include <hip/hip_runtime.h>
#include <math.h>

// ---------------------------------------------------------------------------
// RiemannianPooling: logm(eigh) -> mean -> diff_exp -> cov -> cholesky -> bimap
// N=32, M*T*V=3200, C=16, D=136, out 32x64x64 fp32.
// R6: revert ILP-2 (issue-bound, not latency-bound: R5 567us @39% occ vs R3
//     547us @70% occ). NSWEEP_BIG 8->6. DS/DPP rebalance: masks {4,5,6}
//     (2-DPP composites) moved to ds_swizzle -> 9 DS rounds / 6 single-DPP.
//     k_chol: WbT+Wb staged in LDS, Tout transposed [q][140] for b128 bimap.
//     k_cov: 16-row stages (half the barriers).
// ---------------------------------------------------------------------------

#define EPSV 1e-4f
#define NSWEEP_BIG 6
#define NSWEEP_SMALL 10
#define SQRT2F 1.41421356237309515f

// workspace layout (float offsets) — total 66.5 MB
#define OFF_G      0            // 136
#define OFF_WBT    160          // 137*64 = 8768
#define OFF_MEAN   8960         // 32*136
#define OFF_XM     13312        // 32*136
#define OFF_MPART  320000       // 6400*136 = 870400 (aliases head of PART)
#define OFF_PART   320000       // 8*32*9316 = 2384896 (written after MPART consumed)
#define OFF_L      2704896      // 102400*136

typedef float v2f __attribute__((ext_vector_type(2)));

__device__ __forceinline__ float rcp_f(float x){ return __builtin_amdgcn_rcpf(x); }
__device__ __forceinline__ float rsq_f(float x){ return __builtin_amdgcn_rsqf(x); }

// XOR within 16-lane rows via single DPP (VALU pipe): 1,2,3 quad_perm;
// 7 row_half_mirror; 8 row_ror:8; 15 row_mirror.
template<int R>
__device__ __forceinline__ float xl(float x){
    int s = __float_as_int(x);
    if constexpr (R == 1){
        return __int_as_float(__builtin_amdgcn_update_dpp(s, s, 0xB1, 0xF, 0xF, false));
    } else if constexpr (R == 2){
        return __int_as_float(__builtin_amdgcn_update_dpp(s, s, 0x4E, 0xF, 0xF, false));
    } else if constexpr (R == 3){
        return __int_as_float(__builtin_amdgcn_update_dpp(s, s, 0x1B, 0xF, 0xF, false));
    } else if constexpr (R == 7){
        return __int_as_float(__builtin_amdgcn_update_dpp(s, s, 0x141, 0xF, 0xF, false));
    } else if constexpr (R == 8){
        return __int_as_float(__builtin_amdgcn_update_dpp(s, s, 0x128, 0xF, 0xF, false));
    } else {  // R == 15
        return __int_as_float(__builtin_amdgcn_update_dpp(s, s, 0x140, 0xF, 0xF, false));
    }
}

// Pipe split: masks {4,5,6,9..14} (would need 2 DPPs) -> DS crossbar;
// single-DPP masks {1,2,3,7,8,15} stay on VALU.
template<int R>
__device__ __forceinline__ float shuf(float x){
    if constexpr ((R >= 4 && R <= 6) || R >= 9){
        constexpr int IMM = (R << 10) | 0x1F;   // BitMode: xor=R, and=0x1F
        return __int_as_float(__builtin_amdgcn_ds_swizzle(__float_as_int(x), IMM));
    } else {
        return xl<R>(x);
    }
}

// decode linear lower-tri index d -> (r,c), d = r(r+1)/2 + c
__device__ __forceinline__ void tri_rc(int d, int &r, int &c){
    int rr = (int)floorf((sqrtf(fmaf(8.f, (float)d, 1.f)) - 1.f) * 0.5f);
    if (rr*(rr+1)/2 > d) rr--;
    if ((rr+1)*(rr+2)/2 <= d) rr++;
    r = rr; c = d - rr*(rr+1)/2;
}

// One XOR-tournament round of one-sided Jacobi. 16 lanes per matrix.
template<int R, bool WV>
__device__ __forceinline__ void jac_round(v2f* b, v2f* v, float &nrm, int t){
    v2f pc[8];
#pragma unroll
    for (int i = 0; i < 8; ++i){ pc[i].x = shuf<R>(b[i].x); pc[i].y = shuf<R>(b[i].y); }
    float pn = shuf<R>(nrm);
    v2f g2 = {0.f, 0.f};
#pragma unroll
    for (int i = 0; i < 8; ++i) g2 = g2 + b[i]*pc[i];
    float gam = g2.x + g2.y;
    constexpr int HB = (R & 8) ? 8 : ((R & 4) ? 4 : ((R & 2) ? 2 : 1));
    const bool isp = ((t & HB) == 0);
    float alpha = isp ? nrm : pn;
    float beta  = isp ? pn  : nrm;
    float zeta = (beta - alpha) * 0.5f * rcp_f(gam);
    float tt = copysignf(rcp_f(fabsf(zeta) + sqrtf(fmaf(zeta, zeta, 1.f))), zeta);
    tt = (gam == 0.f) ? 0.f : tt;
    float c = rsq_f(fmaf(tt, tt, 1.f));
    float s = tt * c;
    float ss = isp ? -s  : s;
    float st = isp ? -tt : tt;
    v2f cv = {c, c};
    v2f sv = {ss, ss};
#pragma unroll
    for (int i = 0; i < 8; ++i) b[i] = b[i]*cv + pc[i]*sv;
    if (WV){
        v2f pv[8];
#pragma unroll
        for (int i = 0; i < 8; ++i){ pv[i].x = shuf<R>(v[i].x); pv[i].y = shuf<R>(v[i].y); }
#pragma unroll
        for (int i = 0; i < 8; ++i) v[i] = v[i]*cv + pv[i]*sv;
    }
    nrm = fmaf(st, gam, nrm);
}

template<bool WV>
__device__ __forceinline__ void jac_sweep(v2f* b, v2f* v, float &nrm, int t){
    // Interleave DS rounds {4,5,6,9..14} with DPP rounds {1,2,3,7,8,15}.
    jac_round< 4,WV>(b,v,nrm,t); jac_round< 1,WV>(b,v,nrm,t);
    jac_round< 5,WV>(b,v,nrm,t); jac_round< 2,WV>(b,v,nrm,t);
    jac_round< 6,WV>(b,v,nrm,t); jac_round< 3,WV>(b,v,nrm,t);
    jac_round< 9,WV>(b,v,nrm,t); jac_round< 7,WV>(b,v,nrm,t);
    jac_round<10,WV>(b,v,nrm,t); jac_round< 8,WV>(b,v,nrm,t);
    jac_round<11,WV>(b,v,nrm,t); jac_round<15,WV>(b,v,nrm,t);
    jac_round<12,WV>(b,v,nrm,t); jac_round<13,WV>(b,v,nrm,t);
    jac_round<14,WV>(b,v,nrm,t);
}

// ---------------------------------------------------------------------------
// B: per-matrix eigh + logm lower triangle + per-block mean partials.
//    16 lanes/matrix, 16 matrices/block, 6400 matrix-blocks.
//    Block 6400 = prep (W svd -> G; Wb transpose) hidden under the others.
__global__ __launch_bounds__(256) void k_logm(const float* __restrict__ x,
                                              float* __restrict__ L,
                                              float* __restrict__ mpart,
                                              const float* __restrict__ W,
                                              const float* __restrict__ Wb,
                                              float* __restrict__ ws){
    __shared__ float sm[4608];     // Bl[16][272] + cof[16][16]  (18.4 KB)
    const int tid = threadIdx.x;
    const int t = tid & 15;
    const int g = tid >> 4;
    if (blockIdx.x == 6400){
        // ---- prep: s = svd(W_sym) desc -> G; WbT transpose ----
        float* sigv  = sm;          // 16
        float* s_srt = sm + 16;     // 16
        if (tid < 64){
            v2f b[8]; float nrm = 0.f;
            float* bf = (float*)b;
#pragma unroll
            for (int i = 0; i < 16; ++i){
                float val = 0.5f * (W[i*16 + t] + W[t*16 + i]);
                bf[i] = val;
                nrm = fmaf(val, val, nrm);
            }
#pragma unroll 1
            for (int sw = 0; sw < NSWEEP_SMALL; ++sw) jac_sweep<false>(b, b, nrm, t);
            float n2 = 0.f;
#pragma unroll
            for (int i = 0; i < 16; ++i) n2 = fmaf(bf[i], bf[i], n2);
            float sig = sqrtf(n2);
            if (tid < 16) sigv[t] = sig;
        }
        __syncthreads();
        if (tid < 16){
            float sig = sigv[t];
            int rank = 0;
#pragma unroll
            for (int u = 0; u < 16; ++u){
                float su = sigv[u];
                rank += (su > sig || (su == sig && u < t)) ? 1 : 0;
            }
            s_srt[rank] = sig;   // descending, matches jnp.linalg.svd order
        }
        for (int e = tid; e < 8768; e += 256){
            int o = e / 137, i = e - o*137;
            ws[OFF_WBT + i*64 + o] = Wb[e];
        }
        __syncthreads();
        if (tid < 136){
            int r, c; tri_rc(tid, r, c);
            float sr = s_srt[r], sc = s_srt[c];
            float den = sr - sc;
            bool eq = fabsf(den) < EPSV;
            float er = expf(sr), ec = expf(sc);
            float num = eq ? 0.5f*(er + ec) : (er - ec);
            float dd  = eq ? 1.f : den;
            float scale = (r == c) ? 1.f : SQRT2F;
            ws[OFF_G + tid] = scale * num / dd;
        }
        return;
    }
    float* Bl  = sm;               // g*272 + i*17 + t
    float* cof = sm + 4352;        // g*16 + j
    const size_t m = (size_t)blockIdx.x * 16 + g;
    const float* xp = x + m * 256;
    v2f b[8]; float nrm = 0.f;
    float* bf = (float*)b;
#pragma unroll
    for (int i = 0; i < 16; ++i){
        float val = xp[i*16 + t];
        bf[i] = val;
        nrm = fmaf(val, val, nrm);
    }
#pragma unroll 1
    for (int sw = 0; sw < NSWEEP_BIG; ++sw) jac_sweep<false>(b, b, nrm, t);
    // eigenvalue = ||b||, eigenvector = b/||b|| (SPD: eigs >= 0.5, clamp inert)
    float n2 = 0.f;
#pragma unroll
    for (int i = 0; i < 16; ++i) n2 = fmaf(bf[i], bf[i], n2);
    float lam = sqrtf(n2);
    float w = logf(fmaxf(lam, EPSV));
    float coef = w / n2;            // logm = sum_j coef_j b_j b_j^T
#pragma unroll
    for (int i = 0; i < 16; ++i) Bl[g*272 + i*17 + t] = bf[i];
    cof[g*16 + t] = coef;
    __syncthreads();
    float outv[9];
    float* Lp = L + m * 136;
#pragma unroll
    for (int k = 0; k < 9; ++k){
        int d = t + 16*k;
        float acc = 0.f;
        if (d < 136){
            int r, c; tri_rc(d, r, c);
#pragma unroll
            for (int j = 0; j < 16; ++j)
                acc = fmaf(cof[g*16 + j] * Bl[g*272 + r*17 + j], Bl[g*272 + c*17 + j], acc);
            Lp[d] = acc;
        }
        outv[k] = acc;
    }
    __syncthreads();                // all Bl reads done; alias as reduction buffer
    float* red = sm;                // red[g*144 + d]
#pragma unroll
    for (int k = 0; k < 9; ++k){
        int d = t + 16*k;
        red[g*144 + d] = outv[k];   // zeros for d>=136
    }
    __syncthreads();
    if (tid < 136){
        float s = 0.f;
#pragma unroll
        for (int gg = 0; gg < 16; ++gg) s += red[gg*144 + tid];
        mpart[(size_t)blockIdx.x * 136 + tid] = s;
    }
}

// ---------------------------------------------------------------------------
// C: finalize mean from 200 block-partials per n. 136 active threads.
__global__ __launch_bounds__(256) void k_xm_mean(float* __restrict__ ws){
    const int n = blockIdx.x;
    const int tid = threadIdx.x;
    if (tid < 136){
        const float* mp = ws + OFF_MPART + (size_t)n * 200 * 136 + tid;
        float s = 0.f;
#pragma unroll 4
        for (int c = 0; c < 200; ++c) s += mp[(size_t)c * 136];
        ws[OFF_MEAN + n*136 + tid] = s * (1.f/3200.f);
    }
}

// ---------------------------------------------------------------------------
// E: blocks 0..255: partial covariance (xc = G*(L-mean), 8x4 tiles, 16-p stages).
//    blocks 256..287: xm = lower_triangle(sym_logm(mean)) — hidden under cov.
__global__ __launch_bounds__(512) void k_cov(float* __restrict__ ws){
    __shared__ __align__(16) float xc[16][136];
    __shared__ __align__(16) float Gl[136];
    __shared__ __align__(16) float Ml[136];
    const int bid = blockIdx.x;
    const int tid = threadIdx.x;
    if (bid >= 256){
        // ---- xm for n = bid-256 (V tracked; SIGNED eigenvalue feeds clamp) ----
        const int n = bid - 256;
        float* smf = &xc[0][0];        // scratch
        float* Ms  = smf;              // 136
        float* Vl  = smf + 144;        // 16*20
        float* Hl2 = smf + 464;        // 16*20
        if (tid < 136) Ms[tid] = ws[OFF_MEAN + n*136 + tid];
        __syncthreads();
        const int t = tid & 15;
        if (tid < 64){
            v2f b[8], v[8]; float nrm = 0.f;
            float* bf = (float*)b;
            float* vf = (float*)v;
#pragma unroll
            for (int i = 0; i < 16; ++i){
                int r = (i > t) ? i : t, c = (i > t) ? t : i;
                bf[i] = Ms[r*(r+1)/2 + c];
                vf[i] = (i == t) ? 1.f : 0.f;
                nrm = fmaf(bf[i], bf[i], nrm);
            }
#pragma unroll 1
            for (int sw = 0; sw < NSWEEP_SMALL; ++sw) jac_sweep<true>(b, v, nrm, t);
            float lam = 0.f;
#pragma unroll
            for (int i = 0; i < 16; ++i) lam = fmaf(vf[i], bf[i], lam);  // signed
            float w = logf(fmaxf(lam, EPSV));
            if (tid < 16){
#pragma unroll
                for (int i = 0; i < 16; ++i){ Vl[i*20 + t] = vf[i]; Hl2[i*20 + t] = w * vf[i]; }
            }
        }
        __syncthreads();
        if (tid < 16){
            for (int k = 0; k < 9; ++k){
                int d = t + 16*k;
                if (d < 136){
                    int r, c; tri_rc(d, r, c);
                    float acc = 0.f;
#pragma unroll
                    for (int j = 0; j < 16; ++j) acc = fmaf(Hl2[r*20 + j], Vl[c*20 + j], acc);
                    float scale = (r == c) ? 1.f : SQRT2F;
                    ws[OFF_XM + n*136 + d] = scale * acc;
                }
            }
        }
        return;
    }
    // ---- cov partials ----
    const int n = bid & 31, c8 = bid >> 5;   // c8 in 0..7, 400 p each
    if (tid < 136){
        Gl[tid] = ws[OFF_G + tid];
        Ml[tid] = ws[OFF_MEAN + n*136 + tid];
    }
    int bi = 0, bj = 0; const bool val = (tid < 306);
    if (val){
        int T = tid;
        int bb = (int)floorf((sqrtf(fmaf(4.f, (float)T, 1.f)) - 1.f) * 0.5f);
        while (bb*bb + bb > T) bb--;
        while ((bb+1)*(bb+1) + (bb+1) <= T) bb++;
        bi = bb; bj = T - bb*bb - bb;
    }
    float a0[32];
#pragma unroll
    for (int i = 0; i < 32; ++i) a0[i] = 0.f;
    const float* Lbase = ws + OFF_L + (size_t)n * 3200 * 136;
    for (int st = 0; st < 25; ++st){
        __syncthreads();
        int p0 = c8*400 + st*16;
        for (int f = tid; f < 544; f += 512){
            int pp = f / 34, dd = f - pp*34;
            float4 lv = *(const float4*)(Lbase + (size_t)(p0+pp)*136 + dd*4);
            float4 gv = *(const float4*)(&Gl[dd*4]);
            float4 mv = *(const float4*)(&Ml[dd*4]);
            float4 r;
            r.x = (lv.x - mv.x) * gv.x; r.y = (lv.y - mv.y) * gv.y;
            r.z = (lv.z - mv.z) * gv.z; r.w = (lv.w - mv.w) * gv.w;
            *(float4*)(&xc[pp][dd*4]) = r;
        }
        __syncthreads();
        if (val){
#pragma unroll 1
            for (int pp = 0; pp < 16; ++pp){
                const float4 u0 = *(const float4*)(&xc[pp][bi*8]);
                const float4 u1 = *(const float4*)(&xc[pp][bi*8+4]);
                const float4 w4 = *(const float4*)(&xc[pp][bj*4]);
                float ui[8] = {u0.x,u0.y,u0.z,u0.w,u1.x,u1.y,u1.z,u1.w};
                float wj[4] = {w4.x,w4.y,w4.z,w4.w};
#pragma unroll
                for (int di = 0; di < 8; ++di)
#pragma unroll
                    for (int dj = 0; dj < 4; ++dj)
                        a0[di*4+dj] = fmaf(ui[di], wj[dj], a0[di*4+dj]);
            }
        }
    }
    if (val){
        float* part = ws + OFF_PART + ((size_t)c8*32 + n)*9316;
#pragma unroll
        for (int di = 0; di < 8; ++di){
            int i = bi*8 + di;
#pragma unroll
            for (int dj = 0; dj < 4; ++dj){
                int j = bj*4 + dj;
                if (j <= i) part[i*(i+1)/2 + j] = a0[di*4+dj];
            }
        }
    }
}

// ---------------------------------------------------------------------------
// F: sum partials -> cov -> Cholesky (tri-packed LDS) -> trace -> Tout (LDS,
//    transposed [q][140]) -> out = Wb @ Tout. All operands LDS-resident.
__global__ __launch_bounds__(256) void k_chol(float* __restrict__ ws,
                                              const float* __restrict__ Wb,
                                              float* __restrict__ out){
    __shared__ float T[9316];       // tri-packed cov/chol; later re-staged as Wb[64][140]
    __shared__ float Wt[8768];      // WbT staged: Wt[j*64+q]
    __shared__ float Tt[8960];      // Tout transposed: Tt[q*140+i]
    __shared__ float xr[137];
    __shared__ float trs[2];
    const int n = blockIdx.x;
    const int tid = threadIdx.x;
    for (int e = tid; e < 9316; e += 256){
        float s = 0.f;
#pragma unroll
        for (int c = 0; c < 8; ++c) s += ws[OFF_PART + ((size_t)c*32 + n)*9316 + e];
        T[e] = s * (1.f/3199.f);
    }
    for (int e = tid; e < 8768; e += 256) Wt[e] = ws[OFF_WBT + e];
    if (tid < 136) xr[tid] = ws[OFF_XM + n*136 + tid];
    __syncthreads();
    for (int k = 0; k < 136; ++k){
        const int kb = k*(k+1)/2;
        float dkk = T[kb + k];
        float d = sqrtf(dkk);
        float rinv = 1.f / d;
        __syncthreads();
        for (int i = k+1+tid; i < 136; i += 256) T[i*(i+1)/2 + k] *= rinv;
        if (tid == 0) T[kb + k] = d;
        __syncthreads();
        const int m = 135 - k;
        const int cnt = m*(m+1)/2;
        const int Lc = (cnt + 255) >> 8;
        int e0 = tid * Lc, e1 = e0 + Lc; if (e1 > cnt) e1 = cnt;
        if (e0 < e1){
            float A = 2.f*m + 1.f;
            int jp = (int)floorf((A - sqrtf(fmaf(A, A, -8.f*e0))) * 0.5f);
            if (jp < 0) jp = 0;
            while (jp > 0 && jp*m - jp*(jp-1)/2 > e0) jp--;
            while ((jp+1)*m - (jp+1)*jp/2 <= e0) jp++;
            int ip = jp + (e0 - (jp*m - jp*(jp-1)/2));
            int i = k+1+ip, j = k+1+jp;
            int bI = i*(i+1)/2;
            int idx_ij = bI + j, idx_ik = bI + k;
            float cj = T[j*(j+1)/2 + k];
            for (int e = e0; e < e1; ++e){
                T[idx_ij] -= T[idx_ik] * cj;
                i++;
                if (i == 136){
                    j++; i = j;
                    int bb = i*(i+1)/2;
                    idx_ij = bb + j; idx_ik = bb + k;
                    cj = T[idx_ik];
                } else {
                    idx_ij += i; idx_ik += i;
                }
            }
        }
        __syncthreads();
    }
    if (tid == 0){
        float tr = 1.f;
        for (int kk = 0; kk < 136; ++kk) tr += T[kk*(kk+1)/2 + kk];
        trs[0] = tr; trs[1] = 1.f / tr;
    }
    __syncthreads();
    const float tr = trs[0], itr = trs[1];
    const float c6 = tr * 1e-6f;
    const int q = tid & 63, wv = tid >> 6;
    // Tout rows i == wv (mod 4): Tt[q*140+i] = itr*sum_{j<=i} T[i][j]*Wt[j][q] + c6*Wt[i][q]
#pragma unroll 1
    for (int k = 0; k < 34; ++k){
        int i = wv + 4*k;
        const int ib = i*(i+1)/2;
        float acc = 0.f;
        for (int j = 0; j <= i; ++j) acc = fmaf(T[ib + j], Wt[j*64 + q], acc);
        Tt[q*140 + i] = fmaf(c6, Wt[i*64 + q], itr * acc);
    }
    if (wv == 0){
        float acc = Wt[136*64 + q];            // out[D][D] = 1
        for (int j = 0; j < 136; ++j) acc = fmaf(xr[j], Wt[j*64 + q], acc);
        Tt[q*140 + 136] = fmaf(c6, Wt[136*64 + q], itr * acc);
    }
    __syncthreads();
    // re-stage Wb [64][137] into T as [64][140] (T dead after chol/Tout)
    for (int e = tid; e < 8768; e += 256){
        int o = e / 137, i = e - o*137;
        T[o*140 + i] = Wb[e];
    }
    __syncthreads();
    // bimap: out[n][o][q] = sum_i Wb[o][i] * Tout[i][q], b128 over i
#pragma unroll 1
    for (int o = wv; o < 64; o += 4){
        float acc = 0.f;
#pragma unroll 1
        for (int i4 = 0; i4 < 34; ++i4){
            const float4 wv4 = *(const float4*)(&T[o*140 + 4*i4]);
            const float4 tv4 = *(const float4*)(&Tt[q*140 + 4*i4]);
            acc = fmaf(wv4.x, tv4.x, acc);
            acc = fmaf(wv4.y, tv4.y, acc);
            acc = fmaf(wv4.z, tv4.z, acc);
            acc = fmaf(wv4.w, tv4.w, acc);
        }
        acc = fmaf(T[o*140 + 136], Tt[q*140 + 136], acc);
        out[(size_t)n*4096 + o*64 + q] = acc;
    }
}

// ---------------------------------------------------------------------------
extern "C" void kernel_launch(void* const* d_in, const int* in_sizes, int n_in,
                              void* d_out, int out_size, void* d_ws, size_t ws_size,
                              hipStream_t stream){
    const float* x   = (const float*)d_in[0];
    const float* W   = (const float*)d_in[1];
    const float* Wb  = (const float*)d_in[2];
    float* out = (float*)d_out;
    float* ws  = (float*)d_ws;

    k_logm   <<<6401, 256, 0, stream>>>(x, ws + OFF_L, ws + OFF_MPART, W, Wb, ws);
    k_xm_mean<<<  32, 256, 0, stream>>>(ws);
    k_cov    <<< 288, 512, 0, stream>>>(ws);
    k_chol   <<<  32, 256, 0, stream>>>(ws, Wb, out);
}

// Round 7
// 826.492 us; speedup vs baseline: 1.5308x; 1.0535x over previous
//
#include <hip/hip_runtime.h>
#include <math.h>

// ---------------------------------------------------------------------------
// RiemannianPooling: logm(eigh) -> mean -> diff_exp -> cov -> cholesky -> bimap
// N=32, M*T*V=3200, C=16, D=136, out 32x64x64 fp32.
// R7: k_chol rewrite — full-matrix T stride 141 (bank-conflict-free column
//     walks), col-k staged in separate ck[] + batch-8 RMW (breaks the LDS
//     read-write serialization), 512 threads. Rest frozen from R6.
// ---------------------------------------------------------------------------

#define EPSV 1e-4f
#define NSWEEP_BIG 6
#define NSWEEP_SMALL 10
#define SQRT2F 1.41421356237309515f

// workspace layout (float offsets) — total 66.5 MB
#define OFF_G      0            // 136
#define OFF_WBT    160          // 137*64 = 8768
#define OFF_MEAN   8960         // 32*136
#define OFF_XM     13312        // 32*136
#define OFF_MPART  320000       // 6400*136 (aliases head of PART)
#define OFF_PART   320000       // 8*32*9316 (written after MPART consumed)
#define OFF_L      2704896      // 102400*136

typedef float v2f __attribute__((ext_vector_type(2)));

__device__ __forceinline__ float rcp_f(float x){ return __builtin_amdgcn_rcpf(x); }
__device__ __forceinline__ float rsq_f(float x){ return __builtin_amdgcn_rsqf(x); }

// XOR within 16-lane rows via single DPP (VALU pipe).
template<int R>
__device__ __forceinline__ float xl(float x){
    int s = __float_as_int(x);
    if constexpr (R == 1){
        return __int_as_float(__builtin_amdgcn_update_dpp(s, s, 0xB1, 0xF, 0xF, false));
    } else if constexpr (R == 2){
        return __int_as_float(__builtin_amdgcn_update_dpp(s, s, 0x4E, 0xF, 0xF, false));
    } else if constexpr (R == 3){
        return __int_as_float(__builtin_amdgcn_update_dpp(s, s, 0x1B, 0xF, 0xF, false));
    } else if constexpr (R == 7){
        return __int_as_float(__builtin_amdgcn_update_dpp(s, s, 0x141, 0xF, 0xF, false));
    } else if constexpr (R == 8){
        return __int_as_float(__builtin_amdgcn_update_dpp(s, s, 0x128, 0xF, 0xF, false));
    } else {  // R == 15
        return __int_as_float(__builtin_amdgcn_update_dpp(s, s, 0x140, 0xF, 0xF, false));
    }
}

// Pipe split: masks {4,5,6,9..14} -> DS crossbar; {1,2,3,7,8,15} on VALU DPP.
template<int R>
__device__ __forceinline__ float shuf(float x){
    if constexpr ((R >= 4 && R <= 6) || R >= 9){
        constexpr int IMM = (R << 10) | 0x1F;   // BitMode: xor=R, and=0x1F
        return __int_as_float(__builtin_amdgcn_ds_swizzle(__float_as_int(x), IMM));
    } else {
        return xl<R>(x);
    }
}

// decode linear lower-tri index d -> (r,c), d = r(r+1)/2 + c
__device__ __forceinline__ void tri_rc(int d, int &r, int &c){
    int rr = (int)floorf((sqrtf(fmaf(8.f, (float)d, 1.f)) - 1.f) * 0.5f);
    if (rr*(rr+1)/2 > d) rr--;
    if ((rr+1)*(rr+2)/2 <= d) rr++;
    r = rr; c = d - rr*(rr+1)/2;
}

// One XOR-tournament round of one-sided Jacobi. 16 lanes per matrix.
template<int R, bool WV>
__device__ __forceinline__ void jac_round(v2f* b, v2f* v, float &nrm, int t){
    v2f pc[8];
#pragma unroll
    for (int i = 0; i < 8; ++i){ pc[i].x = shuf<R>(b[i].x); pc[i].y = shuf<R>(b[i].y); }
    float pn = shuf<R>(nrm);
    v2f g2 = {0.f, 0.f};
#pragma unroll
    for (int i = 0; i < 8; ++i) g2 = g2 + b[i]*pc[i];
    float gam = g2.x + g2.y;
    constexpr int HB = (R & 8) ? 8 : ((R & 4) ? 4 : ((R & 2) ? 2 : 1));
    const bool isp = ((t & HB) == 0);
    float alpha = isp ? nrm : pn;
    float beta  = isp ? pn  : nrm;
    float zeta = (beta - alpha) * 0.5f * rcp_f(gam);
    float tt = copysignf(rcp_f(fabsf(zeta) + sqrtf(fmaf(zeta, zeta, 1.f))), zeta);
    tt = (gam == 0.f) ? 0.f : tt;
    float c = rsq_f(fmaf(tt, tt, 1.f));
    float s = tt * c;
    float ss = isp ? -s  : s;
    float st = isp ? -tt : tt;
    v2f cv = {c, c};
    v2f sv = {ss, ss};
#pragma unroll
    for (int i = 0; i < 8; ++i) b[i] = b[i]*cv + pc[i]*sv;
    if (WV){
        v2f pv[8];
#pragma unroll
        for (int i = 0; i < 8; ++i){ pv[i].x = shuf<R>(v[i].x); pv[i].y = shuf<R>(v[i].y); }
#pragma unroll
        for (int i = 0; i < 8; ++i) v[i] = v[i]*cv + pv[i]*sv;
    }
    nrm = fmaf(st, gam, nrm);
}

template<bool WV>
__device__ __forceinline__ void jac_sweep(v2f* b, v2f* v, float &nrm, int t){
    jac_round< 4,WV>(b,v,nrm,t); jac_round< 1,WV>(b,v,nrm,t);
    jac_round< 5,WV>(b,v,nrm,t); jac_round< 2,WV>(b,v,nrm,t);
    jac_round< 6,WV>(b,v,nrm,t); jac_round< 3,WV>(b,v,nrm,t);
    jac_round< 9,WV>(b,v,nrm,t); jac_round< 7,WV>(b,v,nrm,t);
    jac_round<10,WV>(b,v,nrm,t); jac_round< 8,WV>(b,v,nrm,t);
    jac_round<11,WV>(b,v,nrm,t); jac_round<15,WV>(b,v,nrm,t);
    jac_round<12,WV>(b,v,nrm,t); jac_round<13,WV>(b,v,nrm,t);
    jac_round<14,WV>(b,v,nrm,t);
}

// ---------------------------------------------------------------------------
// B: per-matrix eigh + logm lower triangle + per-block mean partials.
__global__ __launch_bounds__(256) void k_logm(const float* __restrict__ x,
                                              float* __restrict__ L,
                                              float* __restrict__ mpart,
                                              const float* __restrict__ W,
                                              const float* __restrict__ Wb,
                                              float* __restrict__ ws){
    __shared__ float sm[4608];     // Bl[16][272] + cof[16][16]  (18.4 KB)
    const int tid = threadIdx.x;
    const int t = tid & 15;
    const int g = tid >> 4;
    if (blockIdx.x == 6400){
        // ---- prep: s = svd(W_sym) desc -> G; WbT transpose ----
        float* sigv  = sm;          // 16
        float* s_srt = sm + 16;     // 16
        if (tid < 64){
            v2f b[8]; float nrm = 0.f;
            float* bf = (float*)b;
#pragma unroll
            for (int i = 0; i < 16; ++i){
                float val = 0.5f * (W[i*16 + t] + W[t*16 + i]);
                bf[i] = val;
                nrm = fmaf(val, val, nrm);
            }
#pragma unroll 1
            for (int sw = 0; sw < NSWEEP_SMALL; ++sw) jac_sweep<false>(b, b, nrm, t);
            float n2 = 0.f;
#pragma unroll
            for (int i = 0; i < 16; ++i) n2 = fmaf(bf[i], bf[i], n2);
            float sig = sqrtf(n2);
            if (tid < 16) sigv[t] = sig;
        }
        __syncthreads();
        if (tid < 16){
            float sig = sigv[t];
            int rank = 0;
#pragma unroll
            for (int u = 0; u < 16; ++u){
                float su = sigv[u];
                rank += (su > sig || (su == sig && u < t)) ? 1 : 0;
            }
            s_srt[rank] = sig;   // descending, matches jnp.linalg.svd order
        }
        for (int e = tid; e < 8768; e += 256){
            int o = e / 137, i = e - o*137;
            ws[OFF_WBT + i*64 + o] = Wb[e];
        }
        __syncthreads();
        if (tid < 136){
            int r, c; tri_rc(tid, r, c);
            float sr = s_srt[r], sc = s_srt[c];
            float den = sr - sc;
            bool eq = fabsf(den) < EPSV;
            float er = expf(sr), ec = expf(sc);
            float num = eq ? 0.5f*(er + ec) : (er - ec);
            float dd  = eq ? 1.f : den;
            float scale = (r == c) ? 1.f : SQRT2F;
            ws[OFF_G + tid] = scale * num / dd;
        }
        return;
    }
    float* Bl  = sm;               // g*272 + i*17 + t
    float* cof = sm + 4352;        // g*16 + j
    const size_t m = (size_t)blockIdx.x * 16 + g;
    const float* xp = x + m * 256;
    v2f b[8]; float nrm = 0.f;
    float* bf = (float*)b;
#pragma unroll
    for (int i = 0; i < 16; ++i){
        float val = xp[i*16 + t];
        bf[i] = val;
        nrm = fmaf(val, val, nrm);
    }
#pragma unroll 1
    for (int sw = 0; sw < NSWEEP_BIG; ++sw) jac_sweep<false>(b, b, nrm, t);
    float n2 = 0.f;
#pragma unroll
    for (int i = 0; i < 16; ++i) n2 = fmaf(bf[i], bf[i], n2);
    float lam = sqrtf(n2);
    float w = logf(fmaxf(lam, EPSV));
    float coef = w / n2;            // logm = sum_j coef_j b_j b_j^T
#pragma unroll
    for (int i = 0; i < 16; ++i) Bl[g*272 + i*17 + t] = bf[i];
    cof[g*16 + t] = coef;
    __syncthreads();
    float outv[9];
    float* Lp = L + m * 136;
#pragma unroll
    for (int k = 0; k < 9; ++k){
        int d = t + 16*k;
        float acc = 0.f;
        if (d < 136){
            int r, c; tri_rc(d, r, c);
#pragma unroll
            for (int j = 0; j < 16; ++j)
                acc = fmaf(cof[g*16 + j] * Bl[g*272 + r*17 + j], Bl[g*272 + c*17 + j], acc);
            Lp[d] = acc;
        }
        outv[k] = acc;
    }
    __syncthreads();
    float* red = sm;                // red[g*144 + d]
#pragma unroll
    for (int k = 0; k < 9; ++k){
        int d = t + 16*k;
        red[g*144 + d] = outv[k];
    }
    __syncthreads();
    if (tid < 136){
        float s = 0.f;
#pragma unroll
        for (int gg = 0; gg < 16; ++gg) s += red[gg*144 + tid];
        mpart[(size_t)blockIdx.x * 136 + tid] = s;
    }
}

// ---------------------------------------------------------------------------
// C: finalize mean from 200 block-partials per n.
__global__ __launch_bounds__(256) void k_xm_mean(float* __restrict__ ws){
    const int n = blockIdx.x;
    const int tid = threadIdx.x;
    if (tid < 136){
        const float* mp = ws + OFF_MPART + (size_t)n * 200 * 136 + tid;
        float s = 0.f;
#pragma unroll 4
        for (int c = 0; c < 200; ++c) s += mp[(size_t)c * 136];
        ws[OFF_MEAN + n*136 + tid] = s * (1.f/3200.f);
    }
}

// ---------------------------------------------------------------------------
// E: blocks 0..255: partial covariance. blocks 256..287: xm eigendecomp.
__global__ __launch_bounds__(512) void k_cov(float* __restrict__ ws){
    __shared__ __align__(16) float xc[16][136];
    __shared__ __align__(16) float Gl[136];
    __shared__ __align__(16) float Ml[136];
    const int bid = blockIdx.x;
    const int tid = threadIdx.x;
    if (bid >= 256){
        const int n = bid - 256;
        float* smf = &xc[0][0];
        float* Ms  = smf;              // 136
        float* Vl  = smf + 144;        // 16*20
        float* Hl2 = smf + 464;        // 16*20
        if (tid < 136) Ms[tid] = ws[OFF_MEAN + n*136 + tid];
        __syncthreads();
        const int t = tid & 15;
        if (tid < 64){
            v2f b[8], v[8]; float nrm = 0.f;
            float* bf = (float*)b;
            float* vf = (float*)v;
#pragma unroll
            for (int i = 0; i < 16; ++i){
                int r = (i > t) ? i : t, c = (i > t) ? t : i;
                bf[i] = Ms[r*(r+1)/2 + c];
                vf[i] = (i == t) ? 1.f : 0.f;
                nrm = fmaf(bf[i], bf[i], nrm);
            }
#pragma unroll 1
            for (int sw = 0; sw < NSWEEP_SMALL; ++sw) jac_sweep<true>(b, v, nrm, t);
            float lam = 0.f;
#pragma unroll
            for (int i = 0; i < 16; ++i) lam = fmaf(vf[i], bf[i], lam);  // signed
            float w = logf(fmaxf(lam, EPSV));
            if (tid < 16){
#pragma unroll
                for (int i = 0; i < 16; ++i){ Vl[i*20 + t] = vf[i]; Hl2[i*20 + t] = w * vf[i]; }
            }
        }
        __syncthreads();
        if (tid < 16){
            for (int k = 0; k < 9; ++k){
                int d = t + 16*k;
                if (d < 136){
                    int r, c; tri_rc(d, r, c);
                    float acc = 0.f;
#pragma unroll
                    for (int j = 0; j < 16; ++j) acc = fmaf(Hl2[r*20 + j], Vl[c*20 + j], acc);
                    float scale = (r == c) ? 1.f : SQRT2F;
                    ws[OFF_XM + n*136 + d] = scale * acc;
                }
            }
        }
        return;
    }
    const int n = bid & 31, c8 = bid >> 5;
    if (tid < 136){
        Gl[tid] = ws[OFF_G + tid];
        Ml[tid] = ws[OFF_MEAN + n*136 + tid];
    }
    int bi = 0, bj = 0; const bool val = (tid < 306);
    if (val){
        int T = tid;
        int bb = (int)floorf((sqrtf(fmaf(4.f, (float)T, 1.f)) - 1.f) * 0.5f);
        while (bb*bb + bb > T) bb--;
        while ((bb+1)*(bb+1) + (bb+1) <= T) bb++;
        bi = bb; bj = T - bb*bb - bb;
    }
    float a0[32];
#pragma unroll
    for (int i = 0; i < 32; ++i) a0[i] = 0.f;
    const float* Lbase = ws + OFF_L + (size_t)n * 3200 * 136;
    for (int st = 0; st < 25; ++st){
        __syncthreads();
        int p0 = c8*400 + st*16;
        for (int f = tid; f < 544; f += 512){
            int pp = f / 34, dd = f - pp*34;
            float4 lv = *(const float4*)(Lbase + (size_t)(p0+pp)*136 + dd*4);
            float4 gv = *(const float4*)(&Gl[dd*4]);
            float4 mv = *(const float4*)(&Ml[dd*4]);
            float4 r;
            r.x = (lv.x - mv.x) * gv.x; r.y = (lv.y - mv.y) * gv.y;
            r.z = (lv.z - mv.z) * gv.z; r.w = (lv.w - mv.w) * gv.w;
            *(float4*)(&xc[pp][dd*4]) = r;
        }
        __syncthreads();
        if (val){
#pragma unroll 1
            for (int pp = 0; pp < 16; ++pp){
                const float4 u0 = *(const float4*)(&xc[pp][bi*8]);
                const float4 u1 = *(const float4*)(&xc[pp][bi*8+4]);
                const float4 w4 = *(const float4*)(&xc[pp][bj*4]);
                float ui[8] = {u0.x,u0.y,u0.z,u0.w,u1.x,u1.y,u1.z,u1.w};
                float wj[4] = {w4.x,w4.y,w4.z,w4.w};
#pragma unroll
                for (int di = 0; di < 8; ++di)
#pragma unroll
                    for (int dj = 0; dj < 4; ++dj)
                        a0[di*4+dj] = fmaf(ui[di], wj[dj], a0[di*4+dj]);
            }
        }
    }
    if (val){
        float* part = ws + OFF_PART + ((size_t)c8*32 + n)*9316;
#pragma unroll
        for (int di = 0; di < 8; ++di){
            int i = bi*8 + di;
#pragma unroll
            for (int dj = 0; dj < 4; ++dj){
                int j = bj*4 + dj;
                if (j <= i) part[i*(i+1)/2 + j] = a0[di*4+dj];
            }
        }
    }
}

// ---------------------------------------------------------------------------
// F: sum partials -> cov (full-matrix LDS, stride 141) -> Cholesky (ck-staged,
//    batch-8 RMW) -> Tout (Tt[i*64+q]) -> out = Wb @ Tout. 512 threads.
#define TST 141   // T row stride: 141 mod 32 = 13, gcd(13,32)=1 -> conflict-free cols
__global__ __launch_bounds__(512) void k_chol(float* __restrict__ ws,
                                              const float* __restrict__ Wb,
                                              float* __restrict__ out){
    __shared__ float T[136*TST];    // 76.7 KB; later row-stride-144 Wb copy for bimap
    __shared__ float Wt[8768];      // WbT: Wt[j*64+q]
    __shared__ float Tt[8768];      // Tout: Tt[i*64+q]
    __shared__ float ck[136];       // scaled column k (separate object: no aliasing)
    __shared__ float xr[136];
    __shared__ float trs[2];
    const int n = blockIdx.x;
    const int tid = threadIdx.x;
    // stage cov (tri-packed partials -> full lower) + WbT + xm row
    for (int e = tid; e < 9316; e += 512){
        float s = 0.f;
#pragma unroll
        for (int c = 0; c < 8; ++c) s += ws[OFF_PART + ((size_t)c*32 + n)*9316 + e];
        int r, cc2; tri_rc(e, r, cc2);
        T[r*TST + cc2] = s * (1.f/3199.f);
    }
    for (int e = tid; e < 8768; e += 512) Wt[e] = ws[OFF_WBT + e];
    if (tid < 136) xr[tid] = ws[OFF_XM + n*136 + tid];
    __syncthreads();
    // right-looking Cholesky on lower triangle
    for (int k = 0; k < 136; ++k){
        float d = sqrtf(T[k*TST + k]);
        float rinv = 1.f / d;
        {
            int i = k + 1 + tid;
            if (i < 136){
                float v2 = T[i*TST + k] * rinv;
                T[i*TST + k] = v2;
                ck[i] = v2;
            }
            if (tid == 0) T[k*TST + k] = d;
        }
        __syncthreads();
        const int m = 135 - k;
        const int cnt = m*(m+1)/2;
        const int Lc = (cnt + 511) >> 9;
        int e0 = tid * Lc, e1 = e0 + Lc; if (e1 > cnt) e1 = cnt;
        if (e0 < e1){
            float A = 2.f*m + 1.f;
            int jp = (int)floorf((A - sqrtf(fmaf(A, A, -8.f*e0))) * 0.5f);
            if (jp < 0) jp = 0;
            while (jp > 0 && jp*m - jp*(jp-1)/2 > e0) jp--;
            while ((jp+1)*m - (jp+1)*jp/2 <= e0) jp++;
            int ip = jp + (e0 - (jp*m - jp*(jp-1)/2));
            int i = k+1+ip, j = k+1+jp;
            int ix = i*TST + j;
            int e = e0;
            while (e < e1){
                int nb = e1 - e; if (nb > 8) nb = 8;
                int   ixs[8]; float cis[8], cjs[8], tv[8];
#pragma unroll
                for (int b2 = 0; b2 < 8; ++b2){
                    if (b2 < nb){
                        ixs[b2] = ix; cis[b2] = ck[i]; cjs[b2] = ck[j];
                        i++; ix += TST;
                        if (i == 136){ j++; i = j; ix = i*TST + j; }
                    }
                }
#pragma unroll
                for (int b2 = 0; b2 < 8; ++b2) if (b2 < nb) tv[b2] = T[ixs[b2]];
#pragma unroll
                for (int b2 = 0; b2 < 8; ++b2) if (b2 < nb) tv[b2] = fmaf(-cis[b2], cjs[b2], tv[b2]);
#pragma unroll
                for (int b2 = 0; b2 < 8; ++b2) if (b2 < nb) T[ixs[b2]] = tv[b2];
                e += nb;
            }
        }
        __syncthreads();
    }
    if (tid == 0){
        float tr = 1.f;
        for (int kk = 0; kk < 136; ++kk) tr += T[kk*TST + kk];
        trs[0] = tr; trs[1] = 1.f / tr;
    }
    __syncthreads();
    const float tr = trs[0], itr = trs[1];
    const float c6 = tr * 1e-6f;
    const int q = tid & 63, wv = tid >> 6;   // wv in 0..7
    // Tout rows i = wv + 8k: Tt[i*64+q] = itr*sum_{j<=i} T[i][j]*Wt[j][q] + c6*Wt[i][q]
#pragma unroll 1
    for (int kk = 0; kk < 17; ++kk){
        int i = wv + 8*kk;
        const float* Trow = &T[i*TST];
        float acc = 0.f;
        for (int j = 0; j <= i; ++j) acc = fmaf(Trow[j], Wt[j*64 + q], acc);
        Tt[i*64 + q] = fmaf(c6, Wt[i*64 + q], itr * acc);
    }
    if (wv == 0){
        float acc = Wt[136*64 + q];            // out[D][D] = 1
        for (int j = 0; j < 136; ++j) acc = fmaf(xr[j], Wt[j*64 + q], acc);
        Tt[136*64 + q] = fmaf(c6, Wt[136*64 + q], itr * acc);
    }
    __syncthreads();
    // stage Wb [64][137] into T at aligned stride 144 (T dead after Tout)
    for (int e = tid; e < 8768; e += 512){
        int o = e / 137, i2 = e - o*137;
        T[o*144 + i2] = Wb[e];
    }
    __syncthreads();
    // bimap: out[n][o][q] = sum_i Wb[o][i] * Tt[i*64+q]
#pragma unroll 1
    for (int kk = 0; kk < 8; ++kk){
        int o = wv + 8*kk;
        const float* wr = &T[o*144];
        float acc = 0.f;
        for (int i2 = 0; i2 <= 136; ++i2) acc = fmaf(wr[i2], Tt[i2*64 + q], acc);
        out[(size_t)n*4096 + o*64 + q] = acc;
    }
}

// ---------------------------------------------------------------------------
extern "C" void kernel_launch(void* const* d_in, const int* in_sizes, int n_in,
                              void* d_out, int out_size, void* d_ws, size_t ws_size,
                              hipStream_t stream){
    const float* x   = (const float*)d_in[0];
    const float* W   = (const float*)d_in[1];
    const float* Wb  = (const float*)d_in[2];
    float* out = (float*)d_out;
    float* ws  = (float*)d_ws;

    k_logm   <<<6401, 256, 0, stream>>>(x, ws + OFF_L, ws + OFF_MPART, W, Wb, ws);
    k_xm_mean<<<  32, 256, 0, stream>>>(ws);
    k_cov    <<< 288, 512, 0, stream>>>(ws);
    k_chol   <<<  32, 512, 0, stream>>>(ws, Wb, out);
}